// Round 1
// baseline (990.886 us; speedup 1.0000x reference)
//
#include <hip/hip_runtime.h>

// GNNLayer: 3 MLPs (node/message/final). BN folded into GEMM weights.
// bf16 storage, fp32 MFMA accumulation, fp32 stats.
// This round: message-path restructure.
//  - k_gemm_msg2: 192-msg-row (=64 node) tiles, 6 waves; sigmoid/3 reduced in
//    LDS (overlaying the staging buffers), written directly as bf16 into
//    in_f[:,256:512] with fused column stats. No global atomics, no fp32 agg
//    buffer, no zero-fill, no aggfin pass.
//  - k_msgstats2: vectorized short8 loads, one exact pass over PQ.
// Workspace peak unchanged: 68 + 128/Cq MiB, Cq in {1,2,4,8}.

typedef __attribute__((ext_vector_type(8))) short short8;
typedef __attribute__((ext_vector_type(4))) float f32x4;

__device__ __forceinline__ unsigned short f2bu(float f) {
    unsigned int x = __float_as_uint(f);
    x += 0x7fffu + ((x >> 16) & 1u);
    return (unsigned short)(x >> 16);
}
__device__ __forceinline__ float b2f(unsigned short u) {
    return __uint_as_float(((unsigned int)u) << 16);
}
__device__ __forceinline__ float sigmoidf_(float v) {
    return 1.0f / (1.0f + __expf(-v));
}

__global__ __launch_bounds__(256) void k_zero4(float4* p, int n4) {
    int i = blockIdx.x * 256 + threadIdx.x;
    if (i < n4) p[i] = make_float4(0.f, 0.f, 0.f, 0.f);
}

// per-feature sum/sumsq of x [65536,256] (no store)
__global__ __launch_bounds__(256) void k_colstats(const float* __restrict__ x,
                                                  float* __restrict__ ssum,
                                                  float* __restrict__ ssq) {
    const int c = threadIdx.x;
    const int r0 = blockIdx.x * 64;
    float s = 0.f, q = 0.f;
    for (int r = r0; r < r0 + 64; ++r) {
        float v = x[(size_t)r * 256 + c];
        s += v; q += v * v;
    }
    atomicAdd(&ssum[c], s);
    atomicAdd(&ssq[c], q);
}

// fold BN into weights: Bt[j][k] = s_k*W[k][j] (bf16, [N][K]);
// bias[j] (+)= c[j] + sum_k t_k*W[k][j]. One block per output column j.
__global__ __launch_bounds__(256) void k_fold(const float* __restrict__ W,      // [Kc][N]
                                              const float* __restrict__ gamma,
                                              const float* __restrict__ beta,
                                              const float* __restrict__ ssum,
                                              const float* __restrict__ ssq,
                                              const float* __restrict__ cvec,   // [N] or null
                                              float inv_count, int N, int Kc,
                                              unsigned short* __restrict__ Bt,  // [N][Kc]
                                              float* __restrict__ bias, int bias_add) {
    const int j = blockIdx.x;
    const int t = threadIdx.x;
    float part = 0.f;
    for (int k = t; k < Kc; k += 256) {
        float mu  = ssum[k] * inv_count;
        float var = ssq[k] * inv_count - mu * mu;
        float s   = gamma[k] * rsqrtf(var + 1e-5f);
        float tt  = beta[k] - mu * s;
        float w   = W[(size_t)k * N + j];
        Bt[(size_t)j * Kc + k] = f2bu(s * w);
        part += tt * w;
    }
    __shared__ float red[256];
    red[t] = part;
    __syncthreads();
    for (int s2 = 128; s2 > 0; s2 >>= 1) {
        if (t < s2) red[t] += red[t + s2];
        __syncthreads();
    }
    if (t == 0) {
        if (bias_add) atomicAdd(&bias[j], red[0]);
        else bias[j] = red[0] + cvec[j];
    }
}

// stats of h_m = relu(P+Q) over one PQ chunk, vectorized (short8 loads).
// block = 16 graphs; thread: col-group cg (8 cols), sub (4 graphs each).
// Reads each PQ element exactly once (P/Q reuse across the 12 pairs is
// done in registers).
__global__ __launch_bounds__(256) void k_msgstats2(const unsigned short* __restrict__ PQ,
                                                   float* __restrict__ ssum,
                                                   float* __restrict__ ssq) {
    const int cg = threadIdx.x & 63;        // 64 groups x 8 cols = 512
    const int sub = threadIdx.x >> 6;       // 0..3
    const int b0 = blockIdx.x * 16 + sub * 4;
    float s[8] = {}, qq[8] = {};
    for (int g = 0; g < 4; ++g) {
        const int b = b0 + g;
        float Pf[4][8], Qf[4][8];
#pragma unroll
        for (int n = 0; n < 4; ++n) {
            short8 p8 = *(const short8*)(PQ + (size_t)(b * 4 + n) * 1024 + cg * 8);
            short8 q8 = *(const short8*)(PQ + (size_t)(b * 4 + n) * 1024 + 512 + cg * 8);
#pragma unroll
            for (int e = 0; e < 8; ++e) {
                Pf[n][e] = b2f((unsigned short)p8[e]);
                Qf[n][e] = b2f((unsigned short)q8[e]);
            }
        }
#pragma unroll
        for (int si = 0; si < 4; ++si)
#pragma unroll
            for (int di = 0; di < 4; ++di) {
                if (si == di) continue;
#pragma unroll
                for (int e = 0; e < 8; ++e) {
                    float v = fmaxf(Pf[si][e] + Qf[di][e], 0.f);
                    s[e] += v; qq[e] += v * v;
                }
            }
    }
    __shared__ float sS[512], sQ[512];
    sS[threadIdx.x] = 0.f; sS[threadIdx.x + 256] = 0.f;
    sQ[threadIdx.x] = 0.f; sQ[threadIdx.x + 256] = 0.f;
    __syncthreads();
#pragma unroll
    for (int e = 0; e < 8; ++e) {
        atomicAdd(&sS[cg * 8 + e], s[e]);
        atomicAdd(&sQ[cg * 8 + e], qq[e]);
    }
    __syncthreads();
    for (int cidx = threadIdx.x; cidx < 512; cidx += 256) {
        atomicAdd(&ssum[cidx], sS[cidx]);
        atomicAdd(&ssq[cidx], sQ[cidx]);
    }
}

// 128x128-tile bf16 MFMA GEMM, Bt is [N][K]. Manual staging.
// AF32: A operand is fp32 (converted to bf16 during staging).
// EPI: 1 bias+relu+stats bf16; 2 bias+sigmoid+stats bf16; 4 bias+sigmoid f32; 5 bias bf16
template <int EPI, int AF32>
__global__ __launch_bounds__(256) void k_gemm(const void* __restrict__ Av, int lda,
                                              const unsigned short* __restrict__ Bt,
                                              void* __restrict__ C, int ldc,
                                              const float* __restrict__ bias,
                                              float* __restrict__ ssum, float* __restrict__ ssq,
                                              int K) {
    const int n0 = blockIdx.x * 128;
    const int m0 = blockIdx.y * 128;
    const int tid = threadIdx.x;
    const int w = tid >> 6;
    const int lane = tid & 63;
    const int q = lane >> 4;
    const int l = lane & 15;
    const int wm = w >> 1;
    const int wn = w & 1;

    __shared__ __align__(16) unsigned short lA[128 * 32];  // [m][k]
    __shared__ __align__(16) unsigned short lB[128 * 32];  // [n][k]
    __shared__ float s_sum[128];
    __shared__ float s_sq[128];

    if ((EPI == 1 || EPI == 2) && tid < 128) { s_sum[tid] = 0.f; s_sq[tid] = 0.f; }

    f32x4 acc[4][4] = {};

    const int rsub = tid >> 2;          // 0..63
    const int ksub = (tid & 3) * 8;     // 0,8,16,24
    const unsigned short* gA16 = (const unsigned short*)Av + (size_t)(m0 + rsub) * lda + ksub;
    const float*          gA32 = (const float*)Av + (size_t)(m0 + rsub) * lda + ksub;
    const unsigned short* gB = Bt + (size_t)(n0 + rsub) * K + ksub;
    unsigned short* wA = lA + rsub * 32 + ksub;
    unsigned short* wB = lB + rsub * 32 + ksub;

    for (int k0 = 0; k0 < K; k0 += 32) {
        short8 a8[2], b8[2];
#pragma unroll
        for (int t = 0; t < 2; ++t) {
            if (AF32) {
                float4 f0 = *(const float4*)(gA32 + (size_t)t * 64 * lda + k0);
                float4 f1 = *(const float4*)(gA32 + (size_t)t * 64 * lda + k0 + 4);
                short8 o;
                o[0] = (short)f2bu(f0.x); o[1] = (short)f2bu(f0.y);
                o[2] = (short)f2bu(f0.z); o[3] = (short)f2bu(f0.w);
                o[4] = (short)f2bu(f1.x); o[5] = (short)f2bu(f1.y);
                o[6] = (short)f2bu(f1.z); o[7] = (short)f2bu(f1.w);
                a8[t] = o;
            } else {
                a8[t] = *(const short8*)(gA16 + (size_t)t * 64 * lda + k0);
            }
            b8[t] = *(const short8*)(gB + (size_t)t * 64 * K + k0);
        }
        __syncthreads();  // previous iteration's LDS reads complete
#pragma unroll
        for (int t = 0; t < 2; ++t) {
            *(short8*)(wA + t * 64 * 32) = a8[t];
            *(short8*)(wB + t * 64 * 32) = b8[t];
        }
        __syncthreads();
        short8 av[4], bv[4];
#pragma unroll
        for (int i = 0; i < 4; ++i)
            av[i] = *(const short8*)(lA + ((wm * 64 + i * 16 + l) * 32 + q * 8));
#pragma unroll
        for (int j = 0; j < 4; ++j)
            bv[j] = *(const short8*)(lB + ((wn * 64 + j * 16 + l) * 32 + q * 8));
#pragma unroll
        for (int i = 0; i < 4; ++i)
#pragma unroll
            for (int j = 0; j < 4; ++j)
                acc[i][j] = __builtin_amdgcn_mfma_f32_16x16x32_bf16(av[i], bv[j], acc[i][j], 0, 0, 0);
    }

#pragma unroll
    for (int j = 0; j < 4; ++j) {
        const int colL = wn * 64 + j * 16 + l;
        const int col = n0 + colL;
        const float bb = bias[col];
        float psum = 0.f, psq = 0.f;
#pragma unroll
        for (int i = 0; i < 4; ++i) {
            const int rowL = wm * 64 + i * 16 + q * 4;
#pragma unroll
            for (int r = 0; r < 4; ++r) {
                float v = acc[i][j][r] + bb;
                if (EPI == 1) v = fmaxf(v, 0.f);
                if (EPI == 2 || EPI == 4) v = sigmoidf_(v);
                const size_t off = (size_t)(m0 + rowL + r) * ldc + col;
                if (EPI == 4) ((float*)C)[off] = v;
                else ((unsigned short*)C)[off] = f2bu(v);
                psum += v; psq += v * v;
            }
        }
        if (EPI == 1 || EPI == 2) {
            atomicAdd(&s_sum[colL], psum);
            atomicAdd(&s_sq[colL], psq);
        }
    }
    if (EPI == 1 || EPI == 2) {
        __syncthreads();
        if (tid < 128) {
            atomicAdd(&ssum[n0 + tid], s_sum[tid]);
            atomicAdd(&ssq[n0 + tid], s_sq[tid]);
        }
    }
}

// Fused message GEMM + mean-aggregate + bf16 store + column stats.
// Tile: 192 msg rows (= 64 whole nodes, m0 % 3 == 0) x 128 cols, 6 waves.
// A-tile = relu(P[b,si]+Q[b,di]) built on the fly (chunk-local rows).
// Epilogue: sigmoid/3 accumulated into LDS sAgg[64][130] (overlays lA/lB,
// which are dead by then), then written as bf16 into in_f[:,256:512] with
// fused per-column sum/sumsq stats. No global atomics on the output path.
__global__ __launch_bounds__(384) void k_gemm_msg2(const unsigned short* __restrict__ PQ,  // [G][1024] chunk-local
                                                   const unsigned short* __restrict__ Bt,  // A1m [256][512]
                                                   unsigned short* __restrict__ inf_,      // chunk-offset, [G][512] bf16
                                                   const float* __restrict__ bias,         // b1m [256]
                                                   float* __restrict__ ssum,               // sif_s+256
                                                   float* __restrict__ ssq) {              // sif_q+256
    const int K = 512;
    const int n0 = blockIdx.x * 128;
    const int m0 = blockIdx.y * 192;          // chunk-local msg row base, % 3 == 0
    const int tid = threadIdx.x;
    const int w = tid >> 6;                   // 0..5
    const int lane = tid & 63;
    const int q = lane >> 4;
    const int l = lane & 15;
    const int wm = w >> 1;                    // 0..2
    const int wn = w & 1;                     // 0..1

    __shared__ __align__(16) float sAgg[64 * 130];        // 33280 B; overlays lA+lB
    unsigned short* lA = (unsigned short*)sAgg;           // [192][32] = 12288 B
    unsigned short* lB = (unsigned short*)sAgg + 192 * 32;// [128][32] =  8192 B

    f32x4 acc[4][4] = {};

    // A staging: 768 16B-chunks (192 rows x 4), 2 per thread
    unsigned aP[2], aQ[2], wAo[2];
#pragma unroll
    for (int t = 0; t < 2; ++t) {
        int sl = tid + t * 384;
        int lrow = sl >> 2;                   // 0..191
        int kc = (sl & 3) * 8;
        int m = m0 + lrow;
        int b = m / 12;
        int p = m - b * 12;
        int si = p / 3;
        int tt = p - si * 3;
        int di = tt + (tt >= si ? 1 : 0);
        aP[t] = (unsigned)(b * 4 + si) * 1024 + kc;
        aQ[t] = (unsigned)(b * 4 + di) * 1024 + 512 + kc;
        wAo[t] = (unsigned)(lrow * 32 + kc);
    }
    // B staging: 512 chunks; slot tid for all, slot tid+384 for tid<128
    unsigned gBo[2], wBo[2];
#pragma unroll
    for (int t = 0; t < 2; ++t) {
        int sl = tid + t * 384;
        int row = (sl >> 2) & 127;
        int kc = (sl & 3) * 8;
        gBo[t] = (unsigned)(n0 + row) * K + kc;
        wBo[t] = (unsigned)(row * 32 + kc);
    }
    const bool doB1 = (tid < 128);

    for (int k0 = 0; k0 < K; k0 += 32) {
        short8 a8[2], b8[2];
#pragma unroll
        for (int t = 0; t < 2; ++t) {
            short8 p8 = *(const short8*)(PQ + aP[t] + k0);
            short8 q8 = *(const short8*)(PQ + aQ[t] + k0);
            short8 o;
#pragma unroll
            for (int e = 0; e < 8; ++e) {
                float v = b2f((unsigned short)p8[e]) + b2f((unsigned short)q8[e]);
                o[e] = (short)f2bu(fmaxf(v, 0.f));
            }
            a8[t] = o;
        }
        b8[0] = *(const short8*)(Bt + gBo[0] + k0);
        if (doB1) b8[1] = *(const short8*)(Bt + gBo[1] + k0);
        __syncthreads();  // previous iteration's LDS reads complete
#pragma unroll
        for (int t = 0; t < 2; ++t)
            *(short8*)(lA + wAo[t]) = a8[t];
        *(short8*)(lB + wBo[0]) = b8[0];
        if (doB1) *(short8*)(lB + wBo[1]) = b8[1];
        __syncthreads();
        short8 av[4], bv[4];
#pragma unroll
        for (int i = 0; i < 4; ++i)
            av[i] = *(const short8*)(lA + ((wm * 64 + i * 16 + l) * 32 + q * 8));
#pragma unroll
        for (int j = 0; j < 4; ++j)
            bv[j] = *(const short8*)(lB + ((wn * 64 + j * 16 + l) * 32 + q * 8));
#pragma unroll
        for (int i = 0; i < 4; ++i)
#pragma unroll
            for (int j = 0; j < 4; ++j)
                acc[i][j] = __builtin_amdgcn_mfma_f32_16x16x32_bf16(av[i], bv[j], acc[i][j], 0, 0, 0);
    }

    __syncthreads();  // all LDS reads done before overlaying sAgg
    for (int idx = tid; idx < 64 * 130; idx += 384) sAgg[idx] = 0.f;
    __syncthreads();

#pragma unroll
    for (int j = 0; j < 4; ++j) {
        const int colL = wn * 64 + j * 16 + l;
        const float bb = bias[n0 + colL];
#pragma unroll
        for (int i = 0; i < 4; ++i) {
            const int rbase = wm * 64 + i * 16 + q * 4;
#pragma unroll
            for (int r = 0; r < 4; ++r) {
                float v = sigmoidf_(acc[i][j][r] + bb);
                atomicAdd(&sAgg[((rbase + r) / 3) * 130 + colL], v * (1.f / 3.f));
            }
        }
    }
    __syncthreads();

    // write phase: 3 row-subsets x 128 cols
    const int c = tid & 127;
    const int sub = tid >> 7;                 // 0..2
    const int col = n0 + c;
    const int gb = m0 / 3;                    // chunk-local node base
    float s = 0.f, qq = 0.f;
    for (int n = sub; n < 64; n += 3) {
        float v = sAgg[n * 130 + c];
        inf_[(size_t)(gb + n) * 512 + 256 + col] = f2bu(v);
        s += v; qq += v * v;
    }
    atomicAdd(&ssum[col], s);
    atomicAdd(&ssq[col], qq);
}

extern "C" void kernel_launch(void* const* d_in, const int* in_sizes, int n_in,
                              void* d_out, int out_size, void* d_ws, size_t ws_size,
                              hipStream_t stream) {
    const float* x   = (const float*)d_in[0];
    const float* ng0 = (const float*)d_in[1];
    const float* nb0 = (const float*)d_in[2];
    const float* nW0 = (const float*)d_in[3];
    const float* nc0 = (const float*)d_in[4];
    const float* ng1 = (const float*)d_in[5];
    const float* nb1 = (const float*)d_in[6];
    const float* nW1 = (const float*)d_in[7];
    const float* nc1 = (const float*)d_in[8];
    const float* mg0 = (const float*)d_in[9];
    const float* mb0 = (const float*)d_in[10];
    const float* mW0 = (const float*)d_in[11];
    const float* mc0 = (const float*)d_in[12];
    const float* mg1 = (const float*)d_in[13];
    const float* mb1 = (const float*)d_in[14];
    const float* mW1 = (const float*)d_in[15];
    const float* mc1 = (const float*)d_in[16];
    const float* fg0 = (const float*)d_in[17];
    const float* fb0 = (const float*)d_in[18];
    const float* fW0 = (const float*)d_in[19];
    const float* fc0 = (const float*)d_in[20];
    const float* fg1 = (const float*)d_in[21];
    const float* fb1 = (const float*)d_in[22];
    const float* fW1 = (const float*)d_in[23];
    const float* fc1 = (const float*)d_in[24];

    char* ws = (char*)d_ws;
    const size_t MiB = 1024 * 1024;

    // chunk count for PQ: peak ws = 68 + 128/Cq MiB
    int Cq = 1;
    while (Cq < 8 && (68 + 128 / Cq) * MiB > ws_size) Cq *= 2;
    const int G = 65536 / Cq;  // node rows per chunk (multiple of 64)

    // header [0,4MiB): stats (zeroed) + biases + folded weights
    float* stat = (float*)ws;
    float* sx_s   = stat + 0;     // 256
    float* sx_q   = stat + 256;   // 256
    float* shn_s  = stat + 512;   // 512
    float* shn_q  = stat + 1024;
    float* shm_s  = stat + 1536;
    float* shm_q  = stat + 2048;
    float* sif_s  = stat + 2560;
    float* sif_q  = stat + 3072;
    float* shf_s  = stat + 3584;
    float* shf_q  = stat + 4096;  // -> 4608
    float* biasPQ = stat + 4608;  // 1024, upper 512 stay zero
    // zeroed region ends at 5632 floats
    float* bias_n = stat + 5632;  // 512
    float* b1n    = stat + 6144;  // 256
    float* b1m    = stat + 6400;  // 256
    float* b0f    = stat + 6656;  // 512
    float* b1f    = stat + 7168;  // 256

    unsigned short* An  = (unsigned short*)(ws + 256 * 1024);  // [512][256]
    unsigned short* Btm = An + 512 * 256;                      // [1024][256]
    unsigned short* A1n = Btm + 1024 * 256;                    // [256][512]
    unsigned short* A1m = A1n + 256 * 512;                     // [256][512]
    unsigned short* A0f = A1m + 256 * 512;                     // [512][512]
    unsigned short* A1f = A0f + 512 * 512;                     // [256][512]

    // [4,68): hn (bf16, live gemm1..gemm2n) -> hf (bf16, live gemm3..gemm4)
    // [68, 68+128/Cq): PQ chunk buffer
    unsigned short* hn    = (unsigned short*)(ws + 4 * MiB);
    unsigned short* hf    = (unsigned short*)(ws + 4 * MiB);
    unsigned short* PQbuf = (unsigned short*)(ws + 68 * MiB);
    unsigned short* inf   = (unsigned short*)d_out;  // [65536,512] bf16, dead before gemm4

    const float inv1 = 1.f / 65536.f;
    const float invM = 1.f / 196608.f;

    // zero stats + biasPQ (5632 floats = 1408 float4)
    k_zero4<<<6, 256, 0, stream>>>((float4*)stat, 1408);

    // x column stats
    k_colstats<<<1024, 256, 0, stream>>>(x, sx_s, sx_q);

    // fold BN0 (msg BN0 stats == node BN0 stats: each node appears exactly
    // 3x as src and 3x as dst across the 12 ordered pairs)
    k_fold<<<512, 256, 0, stream>>>(nW0, ng0, nb0, sx_s, sx_q, nc0, inv1, 512, 256, An, bias_n, 0);
    k_fold<<<512, 256, 0, stream>>>(mW0, mg0, mb0, sx_s, sx_q, mc0, inv1, 512, 256, Btm, biasPQ, 0);
    k_fold<<<512, 256, 0, stream>>>(mW0 + 256 * 512, mg0 + 256, mb0 + 256, sx_s, sx_q, nullptr,
                                    inv1, 512, 256, Btm + 512 * 256, biasPQ, 1);

    // h_n = relu(x @ An + bias_n), BN1_n stats  (A is fp32 x, staged-converted)
    k_gemm<1, 1><<<dim3(4, 512), 256, 0, stream>>>(x, 256, An, hn, 512, bias_n, shn_s, shn_q, 256);

    // PQ chunks: PQ = x_chunk @ [Amt|Amb] + [bias_m|0]; accumulate BN1_m stats
    for (int c = 0; c < Cq; ++c) {
        k_gemm<5, 1><<<dim3(8, 512 / Cq), 256, 0, stream>>>(
            x + (size_t)c * G * 256, 256, Btm, PQbuf, 1024, biasPQ, nullptr, nullptr, 256);
        k_msgstats2<<<1024 / Cq, 256, 0, stream>>>(PQbuf, shm_s, shm_q);
    }

    // fold BN1
    k_fold<<<256, 256, 0, stream>>>(nW1, ng1, nb1, shn_s, shn_q, nc1, inv1, 256, 512, A1n, b1n, 0);
    k_fold<<<256, 256, 0, stream>>>(mW1, mg1, mb1, shm_s, shm_q, mc1, invM, 256, 512, A1m, b1m, 0);

    // x_node = sigmoid(hn @ A1n + b1n) -> in_f[:,0:256] (in d_out), f-BN0 stats
    k_gemm<2, 0><<<dim3(2, 512), 256, 0, stream>>>(hn, 512, A1n, inf, 512, b1n, sif_s, sif_q, 512);

    // x_agg: fused msg GEMM -> in_f[:,256:512] bf16 + f-BN0 stats (cols 256..511)
    for (int c = 0; c < Cq; ++c) {
        if (Cq > 1)  // recompute PQ chunk (Cq==1 kept the full PQ)
            k_gemm<5, 1><<<dim3(8, 512 / Cq), 256, 0, stream>>>(
                x + (size_t)c * G * 256, 256, Btm, PQbuf, 1024, biasPQ, nullptr, nullptr, 256);
        k_gemm_msg2<<<dim3(2, 1024 / Cq), 384, 0, stream>>>(
            PQbuf, A1m, inf + (size_t)c * G * 512, b1m, sif_s + 256, sif_q + 256);
    }

    // final MLP
    k_fold<<<512, 256, 0, stream>>>(fW0, fg0, fb0, sif_s, sif_q, fc0, inv1, 512, 512, A0f, b0f, 0);
    k_gemm<1, 0><<<dim3(4, 512), 256, 0, stream>>>(inf, 512, A0f, hf, 512, b0f, shf_s, shf_q, 512);
    k_fold<<<256, 256, 0, stream>>>(fW1, fg1, fb1, shf_s, shf_q, fc1, inv1, 256, 512, A1f, b1f, 0);
    k_gemm<4, 0><<<dim3(2, 512), 256, 0, stream>>>(hf, 512, A1f, d_out, 256, b1f, nullptr, nullptr, 512);

    (void)in_sizes; (void)n_in; (void)out_size;
}

// Round 2
// 779.115 us; speedup vs baseline: 1.2718x; 1.2718x over previous
//
#include <hip/hip_runtime.h>

// GNNLayer: 3 MLPs (node/message/final). BN folded into GEMM weights.
// bf16 storage, fp32 MFMA accumulation, fp32 stats.
// Round 2: message GEMM with 4-padded rows (m = 4*node + slot, slot 3 = zero).
// Each lane's acc quad = one node's 3 messages + pad -> mean in registers,
// one coalesced bf16 store into in_f[:,256:512] + fused stats.
// No global atomics, no fp32 agg buffer, no zero-fill, no aggfin pass.
// Proven 256-thread/4-wave/128x128 GEMM structure throughout.

typedef __attribute__((ext_vector_type(8))) short short8;
typedef __attribute__((ext_vector_type(4))) float f32x4;

__device__ __forceinline__ unsigned short f2bu(float f) {
    unsigned int x = __float_as_uint(f);
    x += 0x7fffu + ((x >> 16) & 1u);
    return (unsigned short)(x >> 16);
}
__device__ __forceinline__ float b2f(unsigned short u) {
    return __uint_as_float(((unsigned int)u) << 16);
}
__device__ __forceinline__ float sigmoidf_(float v) {
    return 1.0f / (1.0f + __expf(-v));
}

__global__ __launch_bounds__(256) void k_zero4(float4* p, int n4) {
    int i = blockIdx.x * 256 + threadIdx.x;
    if (i < n4) p[i] = make_float4(0.f, 0.f, 0.f, 0.f);
}

// per-feature sum/sumsq of x [65536,256] (no store)
__global__ __launch_bounds__(256) void k_colstats(const float* __restrict__ x,
                                                  float* __restrict__ ssum,
                                                  float* __restrict__ ssq) {
    const int c = threadIdx.x;
    const int r0 = blockIdx.x * 64;
    float s = 0.f, q = 0.f;
    for (int r = r0; r < r0 + 64; ++r) {
        float v = x[(size_t)r * 256 + c];
        s += v; q += v * v;
    }
    atomicAdd(&ssum[c], s);
    atomicAdd(&ssq[c], q);
}

// fold BN into weights: Bt[j][k] = s_k*W[k][j] (bf16, [N][K]);
// bias[j] (+)= c[j] + sum_k t_k*W[k][j]. One block per output column j.
__global__ __launch_bounds__(256) void k_fold(const float* __restrict__ W,      // [Kc][N]
                                              const float* __restrict__ gamma,
                                              const float* __restrict__ beta,
                                              const float* __restrict__ ssum,
                                              const float* __restrict__ ssq,
                                              const float* __restrict__ cvec,   // [N] or null
                                              float inv_count, int N, int Kc,
                                              unsigned short* __restrict__ Bt,  // [N][Kc]
                                              float* __restrict__ bias, int bias_add) {
    const int j = blockIdx.x;
    const int t = threadIdx.x;
    float part = 0.f;
    for (int k = t; k < Kc; k += 256) {
        float mu  = ssum[k] * inv_count;
        float var = ssq[k] * inv_count - mu * mu;
        float s   = gamma[k] * rsqrtf(var + 1e-5f);
        float tt  = beta[k] - mu * s;
        float w   = W[(size_t)k * N + j];
        Bt[(size_t)j * Kc + k] = f2bu(s * w);
        part += tt * w;
    }
    __shared__ float red[256];
    red[t] = part;
    __syncthreads();
    for (int s2 = 128; s2 > 0; s2 >>= 1) {
        if (t < s2) red[t] += red[t + s2];
        __syncthreads();
    }
    if (t == 0) {
        if (bias_add) atomicAdd(&bias[j], red[0]);
        else bias[j] = red[0] + cvec[j];
    }
}

// stats of h_m = relu(P+Q) over one PQ chunk, vectorized (short8 loads).
// block = 16 graphs; thread: col-group cg (8 cols), sub (4 graphs each).
__global__ __launch_bounds__(256) void k_msgstats2(const unsigned short* __restrict__ PQ,
                                                   float* __restrict__ ssum,
                                                   float* __restrict__ ssq) {
    const int cg = threadIdx.x & 63;        // 64 groups x 8 cols = 512
    const int sub = threadIdx.x >> 6;       // 0..3
    const int b0 = blockIdx.x * 16 + sub * 4;
    float s[8] = {}, qq[8] = {};
    for (int g = 0; g < 4; ++g) {
        const int b = b0 + g;
        float Pf[4][8], Qf[4][8];
#pragma unroll
        for (int n = 0; n < 4; ++n) {
            short8 p8 = *(const short8*)(PQ + (size_t)(b * 4 + n) * 1024 + cg * 8);
            short8 q8 = *(const short8*)(PQ + (size_t)(b * 4 + n) * 1024 + 512 + cg * 8);
#pragma unroll
            for (int e = 0; e < 8; ++e) {
                Pf[n][e] = b2f((unsigned short)p8[e]);
                Qf[n][e] = b2f((unsigned short)q8[e]);
            }
        }
#pragma unroll
        for (int si = 0; si < 4; ++si)
#pragma unroll
            for (int di = 0; di < 4; ++di) {
                if (si == di) continue;
#pragma unroll
                for (int e = 0; e < 8; ++e) {
                    float v = fmaxf(Pf[si][e] + Qf[di][e], 0.f);
                    s[e] += v; qq[e] += v * v;
                }
            }
    }
    __shared__ float sS[512], sQ[512];
    sS[threadIdx.x] = 0.f; sS[threadIdx.x + 256] = 0.f;
    sQ[threadIdx.x] = 0.f; sQ[threadIdx.x + 256] = 0.f;
    __syncthreads();
#pragma unroll
    for (int e = 0; e < 8; ++e) {
        atomicAdd(&sS[cg * 8 + e], s[e]);
        atomicAdd(&sQ[cg * 8 + e], qq[e]);
    }
    __syncthreads();
    for (int cidx = threadIdx.x; cidx < 512; cidx += 256) {
        atomicAdd(&ssum[cidx], sS[cidx]);
        atomicAdd(&ssq[cidx], sQ[cidx]);
    }
}

// 128x128-tile bf16 MFMA GEMM, Bt is [N][K]. Manual staging.
// AF32: A operand is fp32 (converted to bf16 during staging).
// EPI: 1 bias+relu+stats bf16; 2 bias+sigmoid+stats bf16; 4 bias+sigmoid f32; 5 bias bf16
template <int EPI, int AF32>
__global__ __launch_bounds__(256) void k_gemm(const void* __restrict__ Av, int lda,
                                              const unsigned short* __restrict__ Bt,
                                              void* __restrict__ C, int ldc,
                                              const float* __restrict__ bias,
                                              float* __restrict__ ssum, float* __restrict__ ssq,
                                              int K) {
    const int n0 = blockIdx.x * 128;
    const int m0 = blockIdx.y * 128;
    const int tid = threadIdx.x;
    const int w = tid >> 6;
    const int lane = tid & 63;
    const int q = lane >> 4;
    const int l = lane & 15;
    const int wm = w >> 1;
    const int wn = w & 1;

    __shared__ __align__(16) unsigned short lA[128 * 32];  // [m][k]
    __shared__ __align__(16) unsigned short lB[128 * 32];  // [n][k]
    __shared__ float s_sum[128];
    __shared__ float s_sq[128];

    if ((EPI == 1 || EPI == 2) && tid < 128) { s_sum[tid] = 0.f; s_sq[tid] = 0.f; }

    f32x4 acc[4][4] = {};

    const int rsub = tid >> 2;          // 0..63
    const int ksub = (tid & 3) * 8;     // 0,8,16,24
    const unsigned short* gA16 = (const unsigned short*)Av + (size_t)(m0 + rsub) * lda + ksub;
    const float*          gA32 = (const float*)Av + (size_t)(m0 + rsub) * lda + ksub;
    const unsigned short* gB = Bt + (size_t)(n0 + rsub) * K + ksub;
    unsigned short* wA = lA + rsub * 32 + ksub;
    unsigned short* wB = lB + rsub * 32 + ksub;

    for (int k0 = 0; k0 < K; k0 += 32) {
        short8 a8[2], b8[2];
#pragma unroll
        for (int t = 0; t < 2; ++t) {
            if (AF32) {
                float4 f0 = *(const float4*)(gA32 + (size_t)t * 64 * lda + k0);
                float4 f1 = *(const float4*)(gA32 + (size_t)t * 64 * lda + k0 + 4);
                short8 o;
                o[0] = (short)f2bu(f0.x); o[1] = (short)f2bu(f0.y);
                o[2] = (short)f2bu(f0.z); o[3] = (short)f2bu(f0.w);
                o[4] = (short)f2bu(f1.x); o[5] = (short)f2bu(f1.y);
                o[6] = (short)f2bu(f1.z); o[7] = (short)f2bu(f1.w);
                a8[t] = o;
            } else {
                a8[t] = *(const short8*)(gA16 + (size_t)t * 64 * lda + k0);
            }
            b8[t] = *(const short8*)(gB + (size_t)t * 64 * K + k0);
        }
        __syncthreads();  // previous iteration's LDS reads complete
#pragma unroll
        for (int t = 0; t < 2; ++t) {
            *(short8*)(wA + t * 64 * 32) = a8[t];
            *(short8*)(wB + t * 64 * 32) = b8[t];
        }
        __syncthreads();
        short8 av[4], bv[4];
#pragma unroll
        for (int i = 0; i < 4; ++i)
            av[i] = *(const short8*)(lA + ((wm * 64 + i * 16 + l) * 32 + q * 8));
#pragma unroll
        for (int j = 0; j < 4; ++j)
            bv[j] = *(const short8*)(lB + ((wn * 64 + j * 16 + l) * 32 + q * 8));
#pragma unroll
        for (int i = 0; i < 4; ++i)
#pragma unroll
            for (int j = 0; j < 4; ++j)
                acc[i][j] = __builtin_amdgcn_mfma_f32_16x16x32_bf16(av[i], bv[j], acc[i][j], 0, 0, 0);
    }

#pragma unroll
    for (int j = 0; j < 4; ++j) {
        const int colL = wn * 64 + j * 16 + l;
        const int col = n0 + colL;
        const float bb = bias[col];
        float psum = 0.f, psq = 0.f;
#pragma unroll
        for (int i = 0; i < 4; ++i) {
            const int rowL = wm * 64 + i * 16 + q * 4;
#pragma unroll
            for (int r = 0; r < 4; ++r) {
                float v = acc[i][j][r] + bb;
                if (EPI == 1) v = fmaxf(v, 0.f);
                if (EPI == 2 || EPI == 4) v = sigmoidf_(v);
                const size_t off = (size_t)(m0 + rowL + r) * ldc + col;
                if (EPI == 4) ((float*)C)[off] = v;
                else ((unsigned short*)C)[off] = f2bu(v);
                psum += v; psq += v * v;
            }
        }
        if (EPI == 1 || EPI == 2) {
            atomicAdd(&s_sum[colL], psum);
            atomicAdd(&s_sq[colL], psq);
        }
    }
    if (EPI == 1 || EPI == 2) {
        __syncthreads();
        if (tid < 128) {
            atomicAdd(&ssum[n0 + tid], s_sum[tid]);
            atomicAdd(&ssq[n0 + tid], s_sq[tid]);
        }
    }
}

// Fused message GEMM + in-register mean + bf16 store + column stats.
// Padded M: row m = 4*node + slot (slot 0..2 = messages, slot 3 = zero pad).
// 128x128 tiles, 256 threads, 4 waves (the proven k_gemm structure).
// Each lane's acc quad (rows q*4+0..3) = one node's 3 sigmoids + pad ->
// vm = mean in registers, single coalesced bf16 store to in_f[:,256:512].
__global__ __launch_bounds__(256) void k_gemm_msg3(const unsigned short* __restrict__ PQ,  // [G][1024] chunk-local
                                                   const unsigned short* __restrict__ Bt,  // A1m [256][512]
                                                   unsigned short* __restrict__ inf_,      // chunk-offset, [G][512] bf16
                                                   const float* __restrict__ bias,         // b1m [256]
                                                   float* __restrict__ ssum,               // sif_s+256
                                                   float* __restrict__ ssq) {              // sif_q+256
    const int K = 512;
    const int n0 = blockIdx.x * 128;
    const int m0 = blockIdx.y * 128;          // padded chunk-local msg row base
    const int tid = threadIdx.x;
    const int w = tid >> 6;
    const int lane = tid & 63;
    const int q = lane >> 4;
    const int l = lane & 15;
    const int wm = w >> 1;
    const int wn = w & 1;

    __shared__ __align__(16) unsigned short lA[128 * 32];  // [m][k]
    __shared__ __align__(16) unsigned short lB[128 * 32];  // [n][k]
    __shared__ float s_sum[128];
    __shared__ float s_sq[128];

    if (tid < 128) { s_sum[tid] = 0.f; s_sq[tid] = 0.f; }

    f32x4 acc[4][4] = {};

    const int rsub = tid >> 2;          // 0..63
    const int ksub = (tid & 3) * 8;     // 0,8,16,24
    unsigned aP[2], aQ[2];
    bool pad[2];
#pragma unroll
    for (int t = 0; t < 2; ++t) {
        int row = m0 + t * 64 + rsub;    // padded chunk-local msg row
        int node = row >> 2;             // chunk-local node
        int slot = row & 3;
        pad[t] = (slot == 3);
        int si = node & 3;
        int di = slot + (slot >= si ? 1 : 0);
        aP[t] = (unsigned)node * 1024 + ksub;
        aQ[t] = (unsigned)(node - si + di) * 1024 + 512 + ksub;
    }
    const unsigned short* gB = Bt + (size_t)(n0 + rsub) * K + ksub;
    unsigned short* wA = lA + rsub * 32 + ksub;
    unsigned short* wB = lB + rsub * 32 + ksub;

    for (int k0 = 0; k0 < K; k0 += 32) {
        short8 a8[2], b8[2];
#pragma unroll
        for (int t = 0; t < 2; ++t) {
            short8 o;
            if (!pad[t]) {
                short8 p8 = *(const short8*)(PQ + aP[t] + k0);
                short8 q8 = *(const short8*)(PQ + aQ[t] + k0);
#pragma unroll
                for (int e = 0; e < 8; ++e) {
                    float v = b2f((unsigned short)p8[e]) + b2f((unsigned short)q8[e]);
                    o[e] = (short)f2bu(fmaxf(v, 0.f));
                }
            } else {
#pragma unroll
                for (int e = 0; e < 8; ++e) o[e] = 0;
            }
            a8[t] = o;
            b8[t] = *(const short8*)(gB + (size_t)t * 64 * K + k0);
        }
        __syncthreads();  // previous iteration's LDS reads complete
#pragma unroll
        for (int t = 0; t < 2; ++t) {
            *(short8*)(wA + t * 64 * 32) = a8[t];
            *(short8*)(wB + t * 64 * 32) = b8[t];
        }
        __syncthreads();
        short8 av[4], bv[4];
#pragma unroll
        for (int i = 0; i < 4; ++i)
            av[i] = *(const short8*)(lA + ((wm * 64 + i * 16 + l) * 32 + q * 8));
#pragma unroll
        for (int j = 0; j < 4; ++j)
            bv[j] = *(const short8*)(lB + ((wn * 64 + j * 16 + l) * 32 + q * 8));
#pragma unroll
        for (int i = 0; i < 4; ++i)
#pragma unroll
            for (int j = 0; j < 4; ++j)
                acc[i][j] = __builtin_amdgcn_mfma_f32_16x16x32_bf16(av[i], bv[j], acc[i][j], 0, 0, 0);
    }

#pragma unroll
    for (int j = 0; j < 4; ++j) {
        const int colL = wn * 64 + j * 16 + l;
        const int col = n0 + colL;
        const float bb = bias[col];
        float psum = 0.f, psq = 0.f;
#pragma unroll
        for (int i = 0; i < 4; ++i) {
            const int g = (m0 >> 2) + wm * 16 + i * 4 + q;   // chunk-local node row
            float s0 = sigmoidf_(acc[i][j][0] + bb);
            float s1 = sigmoidf_(acc[i][j][1] + bb);
            float s2 = sigmoidf_(acc[i][j][2] + bb);
            float vm = (s0 + s1 + s2) * (1.f / 3.f);
            inf_[(size_t)g * 512 + 256 + col] = f2bu(vm);
            psum += vm; psq += vm * vm;
        }
        atomicAdd(&s_sum[colL], psum);
        atomicAdd(&s_sq[colL], psq);
    }
    __syncthreads();
    if (tid < 128) {
        atomicAdd(&ssum[n0 + tid], s_sum[tid]);
        atomicAdd(&ssq[n0 + tid], s_sq[tid]);
    }
}

extern "C" void kernel_launch(void* const* d_in, const int* in_sizes, int n_in,
                              void* d_out, int out_size, void* d_ws, size_t ws_size,
                              hipStream_t stream) {
    const float* x   = (const float*)d_in[0];
    const float* ng0 = (const float*)d_in[1];
    const float* nb0 = (const float*)d_in[2];
    const float* nW0 = (const float*)d_in[3];
    const float* nc0 = (const float*)d_in[4];
    const float* ng1 = (const float*)d_in[5];
    const float* nb1 = (const float*)d_in[6];
    const float* nW1 = (const float*)d_in[7];
    const float* nc1 = (const float*)d_in[8];
    const float* mg0 = (const float*)d_in[9];
    const float* mb0 = (const float*)d_in[10];
    const float* mW0 = (const float*)d_in[11];
    const float* mc0 = (const float*)d_in[12];
    const float* mg1 = (const float*)d_in[13];
    const float* mb1 = (const float*)d_in[14];
    const float* mW1 = (const float*)d_in[15];
    const float* mc1 = (const float*)d_in[16];
    const float* fg0 = (const float*)d_in[17];
    const float* fb0 = (const float*)d_in[18];
    const float* fW0 = (const float*)d_in[19];
    const float* fc0 = (const float*)d_in[20];
    const float* fg1 = (const float*)d_in[21];
    const float* fb1 = (const float*)d_in[22];
    const float* fW1 = (const float*)d_in[23];
    const float* fc1 = (const float*)d_in[24];

    char* ws = (char*)d_ws;
    const size_t MiB = 1024 * 1024;

    // chunk count for PQ: peak ws = 68 + 128/Cq MiB
    int Cq = 1;
    while (Cq < 8 && (68 + 128 / Cq) * MiB > ws_size) Cq *= 2;
    const int G = 65536 / Cq;  // node rows per chunk (multiple of 32)

    // header [0,4MiB): stats (zeroed) + biases + folded weights
    float* stat = (float*)ws;
    float* sx_s   = stat + 0;     // 256
    float* sx_q   = stat + 256;   // 256
    float* shn_s  = stat + 512;   // 512
    float* shn_q  = stat + 1024;
    float* shm_s  = stat + 1536;
    float* shm_q  = stat + 2048;
    float* sif_s  = stat + 2560;
    float* sif_q  = stat + 3072;
    float* shf_s  = stat + 3584;
    float* shf_q  = stat + 4096;  // -> 4608
    float* biasPQ = stat + 4608;  // 1024, upper 512 stay zero
    // zeroed region ends at 5632 floats
    float* bias_n = stat + 5632;  // 512
    float* b1n    = stat + 6144;  // 256
    float* b1m    = stat + 6400;  // 256
    float* b0f    = stat + 6656;  // 512
    float* b1f    = stat + 7168;  // 256

    unsigned short* An  = (unsigned short*)(ws + 256 * 1024);  // [512][256]
    unsigned short* Btm = An + 512 * 256;                      // [1024][256]
    unsigned short* A1n = Btm + 1024 * 256;                    // [256][512]
    unsigned short* A1m = A1n + 256 * 512;                     // [256][512]
    unsigned short* A0f = A1m + 256 * 512;                     // [512][512]
    unsigned short* A1f = A0f + 512 * 512;                     // [256][512]

    // [4,68): hn (bf16, live gemm1..gemm2n) -> hf (bf16, live gemm3..gemm4)
    // [68, 68+128/Cq): PQ chunk buffer
    unsigned short* hn    = (unsigned short*)(ws + 4 * MiB);
    unsigned short* hf    = (unsigned short*)(ws + 4 * MiB);
    unsigned short* PQbuf = (unsigned short*)(ws + 68 * MiB);
    unsigned short* inf   = (unsigned short*)d_out;  // [65536,512] bf16, dead before gemm4

    const float inv1 = 1.f / 65536.f;
    const float invM = 1.f / 196608.f;

    // zero stats + biasPQ (5632 floats = 1408 float4)
    k_zero4<<<6, 256, 0, stream>>>((float4*)stat, 1408);

    // x column stats
    k_colstats<<<1024, 256, 0, stream>>>(x, sx_s, sx_q);

    // fold BN0 (msg BN0 stats == node BN0 stats: each node appears exactly
    // 3x as src and 3x as dst across the 12 ordered pairs)
    k_fold<<<512, 256, 0, stream>>>(nW0, ng0, nb0, sx_s, sx_q, nc0, inv1, 512, 256, An, bias_n, 0);
    k_fold<<<512, 256, 0, stream>>>(mW0, mg0, mb0, sx_s, sx_q, mc0, inv1, 512, 256, Btm, biasPQ, 0);
    k_fold<<<512, 256, 0, stream>>>(mW0 + 256 * 512, mg0 + 256, mb0 + 256, sx_s, sx_q, nullptr,
                                    inv1, 512, 256, Btm + 512 * 256, biasPQ, 1);

    // h_n = relu(x @ An + bias_n), BN1_n stats  (A is fp32 x, staged-converted)
    k_gemm<1, 1><<<dim3(4, 512), 256, 0, stream>>>(x, 256, An, hn, 512, bias_n, shn_s, shn_q, 256);

    // PQ chunks: PQ = x_chunk @ [Amt|Amb] + [bias_m|0]; accumulate BN1_m stats
    for (int c = 0; c < Cq; ++c) {
        k_gemm<5, 1><<<dim3(8, 512 / Cq), 256, 0, stream>>>(
            x + (size_t)c * G * 256, 256, Btm, PQbuf, 1024, biasPQ, nullptr, nullptr, 256);
        k_msgstats2<<<1024 / Cq, 256, 0, stream>>>(PQbuf, shm_s, shm_q);
    }

    // fold BN1
    k_fold<<<256, 256, 0, stream>>>(nW1, ng1, nb1, shn_s, shn_q, nc1, inv1, 256, 512, A1n, b1n, 0);
    k_fold<<<256, 256, 0, stream>>>(mW1, mg1, mb1, shm_s, shm_q, mc1, invM, 256, 512, A1m, b1m, 0);

    // x_node = sigmoid(hn @ A1n + b1n) -> in_f[:,0:256] (in d_out), f-BN0 stats
    k_gemm<2, 0><<<dim3(2, 512), 256, 0, stream>>>(hn, 512, A1n, inf, 512, b1n, sif_s, sif_q, 512);

    // x_agg: padded msg GEMM -> in_f[:,256:512] bf16 + f-BN0 stats (cols 256..511)
    for (int c = 0; c < Cq; ++c) {
        if (Cq > 1)  // recompute PQ chunk (Cq==1 kept the full PQ)
            k_gemm<5, 1><<<dim3(8, 512 / Cq), 256, 0, stream>>>(
                x + (size_t)c * G * 256, 256, Btm, PQbuf, 1024, biasPQ, nullptr, nullptr, 256);
        k_gemm_msg3<<<dim3(2, G / 32), 256, 0, stream>>>(
            PQbuf, A1m, inf + (size_t)c * G * 512, b1m, sif_s + 256, sif_q + 256);
    }

    // final MLP
    k_fold<<<512, 256, 0, stream>>>(fW0, fg0, fb0, sif_s, sif_q, fc0, inv1, 512, 512, A0f, b0f, 0);
    k_gemm<1, 0><<<dim3(4, 512), 256, 0, stream>>>(inf, 512, A0f, hf, 512, b0f, shf_s, shf_q, 512);
    k_fold<<<256, 256, 0, stream>>>(fW1, fg1, fb1, shf_s, shf_q, fc1, inv1, 256, 512, A1f, b1f, 0);
    k_gemm<4, 0><<<dim3(2, 512), 256, 0, stream>>>(hf, 512, A1f, d_out, 256, b1f, nullptr, nullptr, 512);

    (void)in_sizes; (void)n_in; (void)out_size;
}

// Round 3
// 698.559 us; speedup vs baseline: 1.4185x; 1.1153x over previous
//
#include <hip/hip_runtime.h>

// GNNLayer: 3 MLPs (node/message/final). BN folded into GEMM weights.
// bf16 storage, fp32 MFMA accumulation, fp32 stats.
// Round 3: all GEMM A-operands pre-converted to bf16 (k_xcvt, fused with
// x col-stats); all plain GEMMs stage A and B via global_load_lds width=16
// into double-buffered LDS with a minimal 2-phase pipeline (1 raw barrier +
// vmcnt/lgkm wait per K-step). msg GEMM keeps on-the-fly A (regs->ds_write,
// load-early/convert-late) + DMA B staging.

typedef __attribute__((ext_vector_type(8))) short short8;
typedef __attribute__((ext_vector_type(4))) float f32x4;

__device__ __forceinline__ unsigned short f2bu(float f) {
    unsigned int x = __float_as_uint(f);
    x += 0x7fffu + ((x >> 16) & 1u);
    return (unsigned short)(x >> 16);
}
__device__ __forceinline__ float b2f(unsigned short u) {
    return __uint_as_float(((unsigned int)u) << 16);
}
__device__ __forceinline__ float sigmoidf_(float v) {
    return 1.0f / (1.0f + __expf(-v));
}

// async global->LDS DMA, 16 B per lane; LDS dest = wave-uniform base + lane*16
__device__ __forceinline__ void gld16(const void* g, void* l) {
    __builtin_amdgcn_global_load_lds(
        (const __attribute__((address_space(1))) void*)g,
        (__attribute__((address_space(3))) void*)l, 16, 0, 0);
}

// pipeline barrier: drain DMA + LDS ops, raw barrier (no compiler re-drain)
__device__ __forceinline__ void pipe_barrier() {
    asm volatile("s_waitcnt vmcnt(0) lgkmcnt(0)" ::: "memory");
    __builtin_amdgcn_s_barrier();
    __builtin_amdgcn_sched_barrier(0);
}

__global__ __launch_bounds__(256) void k_zero4(float4* p, int n4) {
    int i = blockIdx.x * 256 + threadIdx.x;
    if (i < n4) p[i] = make_float4(0.f, 0.f, 0.f, 0.f);
}

// x fp32 -> bf16 copy + per-feature sum/sumsq (fused; replaces k_colstats)
__global__ __launch_bounds__(256) void k_xcvt(const float* __restrict__ x,
                                              unsigned short* __restrict__ x16,
                                              float* __restrict__ ssum,
                                              float* __restrict__ ssq) {
    const int c = threadIdx.x;
    const int r0 = blockIdx.x * 64;
    float s = 0.f, q = 0.f;
    for (int r = r0; r < r0 + 64; ++r) {
        float v = x[(size_t)r * 256 + c];
        x16[(size_t)r * 256 + c] = f2bu(v);
        s += v; q += v * v;
    }
    atomicAdd(&ssum[c], s);
    atomicAdd(&ssq[c], q);
}

// fold BN into weights: Bt[j][k] = s_k*W[k][j] (bf16, [N][K]);
// bias[j] (+)= c[j] + sum_k t_k*W[k][j]. One block per output column j.
__global__ __launch_bounds__(256) void k_fold(const float* __restrict__ W,      // [Kc][N]
                                              const float* __restrict__ gamma,
                                              const float* __restrict__ beta,
                                              const float* __restrict__ ssum,
                                              const float* __restrict__ ssq,
                                              const float* __restrict__ cvec,   // [N] or null
                                              float inv_count, int N, int Kc,
                                              unsigned short* __restrict__ Bt,  // [N][Kc]
                                              float* __restrict__ bias, int bias_add) {
    const int j = blockIdx.x;
    const int t = threadIdx.x;
    float part = 0.f;
    for (int k = t; k < Kc; k += 256) {
        float mu  = ssum[k] * inv_count;
        float var = ssq[k] * inv_count - mu * mu;
        float s   = gamma[k] * rsqrtf(var + 1e-5f);
        float tt  = beta[k] - mu * s;
        float w   = W[(size_t)k * N + j];
        Bt[(size_t)j * Kc + k] = f2bu(s * w);
        part += tt * w;
    }
    __shared__ float red[256];
    red[t] = part;
    __syncthreads();
    for (int s2 = 128; s2 > 0; s2 >>= 1) {
        if (t < s2) red[t] += red[t + s2];
        __syncthreads();
    }
    if (t == 0) {
        if (bias_add) atomicAdd(&bias[j], red[0]);
        else bias[j] = red[0] + cvec[j];
    }
}

// stats of h_m = relu(P+Q) over one PQ chunk, vectorized (short8 loads).
__global__ __launch_bounds__(256) void k_msgstats2(const unsigned short* __restrict__ PQ,
                                                   float* __restrict__ ssum,
                                                   float* __restrict__ ssq) {
    const int cg = threadIdx.x & 63;        // 64 groups x 8 cols = 512
    const int sub = threadIdx.x >> 6;       // 0..3
    const int b0 = blockIdx.x * 16 + sub * 4;
    float s[8] = {}, qq[8] = {};
    for (int g = 0; g < 4; ++g) {
        const int b = b0 + g;
        float Pf[4][8], Qf[4][8];
#pragma unroll
        for (int n = 0; n < 4; ++n) {
            short8 p8 = *(const short8*)(PQ + (size_t)(b * 4 + n) * 1024 + cg * 8);
            short8 q8 = *(const short8*)(PQ + (size_t)(b * 4 + n) * 1024 + 512 + cg * 8);
#pragma unroll
            for (int e = 0; e < 8; ++e) {
                Pf[n][e] = b2f((unsigned short)p8[e]);
                Qf[n][e] = b2f((unsigned short)q8[e]);
            }
        }
#pragma unroll
        for (int si = 0; si < 4; ++si)
#pragma unroll
            for (int di = 0; di < 4; ++di) {
                if (si == di) continue;
#pragma unroll
                for (int e = 0; e < 8; ++e) {
                    float v = fmaxf(Pf[si][e] + Qf[di][e], 0.f);
                    s[e] += v; qq[e] += v * v;
                }
            }
    }
    __shared__ float sS[512], sQ[512];
    sS[threadIdx.x] = 0.f; sS[threadIdx.x + 256] = 0.f;
    sQ[threadIdx.x] = 0.f; sQ[threadIdx.x + 256] = 0.f;
    __syncthreads();
#pragma unroll
    for (int e = 0; e < 8; ++e) {
        atomicAdd(&sS[cg * 8 + e], s[e]);
        atomicAdd(&sQ[cg * 8 + e], qq[e]);
    }
    __syncthreads();
    for (int cidx = threadIdx.x; cidx < 512; cidx += 256) {
        atomicAdd(&ssum[cidx], sS[cidx]);
        atomicAdd(&ssq[cidx], sQ[cidx]);
    }
}

// 128x128-tile bf16 MFMA GEMM, A [M][lda] bf16, Bt [N][K] bf16.
// global_load_lds width=16 staging, double-buffered LDS, 2-phase pipeline.
// EPI: 1 bias+relu+stats bf16; 2 bias+sigmoid+stats bf16; 4 bias+sigmoid f32; 5 bias bf16
template <int EPI>
__global__ __launch_bounds__(256) void k_gemm(const unsigned short* __restrict__ A, int lda,
                                              const unsigned short* __restrict__ Bt,
                                              void* __restrict__ C, int ldc,
                                              const float* __restrict__ bias,
                                              float* __restrict__ ssum, float* __restrict__ ssq,
                                              int K) {
    const int n0 = blockIdx.x * 128;
    const int m0 = blockIdx.y * 128;
    const int tid = threadIdx.x;
    const int w = tid >> 6;
    const int lane = tid & 63;
    const int q = lane >> 4;
    const int l = lane & 15;
    const int wm = w >> 1;
    const int wn = w & 1;

    __shared__ __align__(16) unsigned short lA[2][128 * 32];  // [m][k]
    __shared__ __align__(16) unsigned short lB[2][128 * 32];  // [n][k]
    __shared__ float s_sum[128];
    __shared__ float s_sq[128];

    if ((EPI == 1 || EPI == 2) && tid < 128) { s_sum[tid] = 0.f; s_sq[tid] = 0.f; }

    f32x4 acc[4][4] = {};

    const int rsub = tid >> 2;          // 0..63
    const int ksub = (tid & 3) * 8;     // 0,8,16,24
    const unsigned short* gA = A + (size_t)(m0 + rsub) * lda + ksub;
    const unsigned short* gB = Bt + (size_t)(n0 + rsub) * K + ksub;
    const unsigned wofs = (unsigned)(tid >> 6) * 1024;  // wave LDS base, bytes

    auto stage = [&](int buf, int k0) {
        char* la = (char*)lA[buf] + wofs;
        char* lb = (char*)lB[buf] + wofs;
        gld16(gA + k0, la);
        gld16(gA + (size_t)64 * lda + k0, la + 4096);
        gld16(gB + k0, lb);
        gld16(gB + (size_t)64 * K + k0, lb + 4096);
    };

    stage(0, 0);
    pipe_barrier();

    const int nt = K >> 5;
    int cur = 0;
    for (int t = 0; t < nt; ++t) {
        if (t + 1 < nt) stage(cur ^ 1, (t + 1) << 5);
        short8 av[4], bv[4];
#pragma unroll
        for (int i = 0; i < 4; ++i)
            av[i] = *(const short8*)(&lA[cur][(wm * 64 + i * 16 + l) * 32 + q * 8]);
#pragma unroll
        for (int j = 0; j < 4; ++j)
            bv[j] = *(const short8*)(&lB[cur][(wn * 64 + j * 16 + l) * 32 + q * 8]);
#pragma unroll
        for (int i = 0; i < 4; ++i)
#pragma unroll
            for (int j = 0; j < 4; ++j)
                acc[i][j] = __builtin_amdgcn_mfma_f32_16x16x32_bf16(av[i], bv[j], acc[i][j], 0, 0, 0);
        if (t + 1 < nt) pipe_barrier();
        cur ^= 1;
    }

#pragma unroll
    for (int j = 0; j < 4; ++j) {
        const int colL = wn * 64 + j * 16 + l;
        const int col = n0 + colL;
        const float bb = bias[col];
        float psum = 0.f, psq = 0.f;
#pragma unroll
        for (int i = 0; i < 4; ++i) {
            const int rowL = wm * 64 + i * 16 + q * 4;
#pragma unroll
            for (int r = 0; r < 4; ++r) {
                float v = acc[i][j][r] + bb;
                if (EPI == 1) v = fmaxf(v, 0.f);
                if (EPI == 2 || EPI == 4) v = sigmoidf_(v);
                const size_t off = (size_t)(m0 + rowL + r) * ldc + col;
                if (EPI == 4) ((float*)C)[off] = v;
                else ((unsigned short*)C)[off] = f2bu(v);
                psum += v; psq += v * v;
            }
        }
        if (EPI == 1 || EPI == 2) {
            atomicAdd(&s_sum[colL], psum);
            atomicAdd(&s_sq[colL], psq);
        }
    }
    if (EPI == 1 || EPI == 2) {
        __syncthreads();
        if (tid < 128) {
            atomicAdd(&ssum[n0 + tid], s_sum[tid]);
            atomicAdd(&ssq[n0 + tid], s_sq[tid]);
        }
    }
}

// Fused message GEMM + in-register mean + bf16 store + column stats.
// Padded M: row m = 4*node + slot (slot 0..2 = messages, slot 3 = zero pad).
// 2-phase pipeline: p/q loads issued early (regs), convert+ds_write after
// MFMA (latency hidden under compute); B staged via global_load_lds DMA.
__global__ __launch_bounds__(256) void k_gemm_msg3(const unsigned short* __restrict__ PQ,  // [G][1024] chunk-local
                                                   const unsigned short* __restrict__ Bt,  // A1m [256][512]
                                                   unsigned short* __restrict__ inf_,      // chunk-offset, [G][512] bf16
                                                   const float* __restrict__ bias,         // b1m [256]
                                                   float* __restrict__ ssum,               // sif_s+256
                                                   float* __restrict__ ssq) {              // sif_q+256
    const int K = 512;
    const int n0 = blockIdx.x * 128;
    const int m0 = blockIdx.y * 128;          // padded chunk-local msg row base
    const int tid = threadIdx.x;
    const int w = tid >> 6;
    const int lane = tid & 63;
    const int q = lane >> 4;
    const int l = lane & 15;
    const int wm = w >> 1;
    const int wn = w & 1;

    __shared__ __align__(16) unsigned short lA[2][128 * 32];
    __shared__ __align__(16) unsigned short lB[2][128 * 32];
    __shared__ float s_sum[128];
    __shared__ float s_sq[128];

    if (tid < 128) { s_sum[tid] = 0.f; s_sq[tid] = 0.f; }

    f32x4 acc[4][4] = {};

    const int rsub = tid >> 2;          // 0..63
    const int ksub = (tid & 3) * 8;     // 0,8,16,24
    unsigned aP[2], aQ[2], wAo[2];
    bool pad[2];
#pragma unroll
    for (int t = 0; t < 2; ++t) {
        int row = m0 + t * 64 + rsub;    // padded chunk-local msg row
        int node = row >> 2;             // chunk-local node
        int slot = row & 3;
        pad[t] = (slot == 3);
        int si = node & 3;
        int di = slot + (slot >= si ? 1 : 0);
        aP[t] = (unsigned)node * 1024 + ksub;
        aQ[t] = (unsigned)(node - si + di) * 1024 + 512 + ksub;
        wAo[t] = (unsigned)((t * 64 + rsub) * 32 + ksub);
    }
    const unsigned short* gB = Bt + (size_t)(n0 + rsub) * K + ksub;
    const unsigned wofs = (unsigned)(tid >> 6) * 1024;

    auto loadPQ = [&](int k0, short8 p8[2], short8 q8[2]) {
#pragma unroll
        for (int t = 0; t < 2; ++t) {
            if (!pad[t]) {
                p8[t] = *(const short8*)(PQ + aP[t] + k0);
                q8[t] = *(const short8*)(PQ + aQ[t] + k0);
            }
        }
    };
    auto buildA = [&](const short8 p8[2], const short8 q8[2], short8 a8[2]) {
#pragma unroll
        for (int t = 0; t < 2; ++t) {
            short8 o;
            if (!pad[t]) {
#pragma unroll
                for (int e = 0; e < 8; ++e) {
                    float v = b2f((unsigned short)p8[t][e]) + b2f((unsigned short)q8[t][e]);
                    o[e] = (short)f2bu(fmaxf(v, 0.f));
                }
            } else {
#pragma unroll
                for (int e = 0; e < 8; ++e) o[e] = 0;
            }
            a8[t] = o;
        }
    };
    auto stageB = [&](int buf, int k0) {
        char* lb = (char*)lB[buf] + wofs;
        gld16(gB + k0, lb);
        gld16(gB + (size_t)64 * K + k0, lb + 4096);
    };

    // prologue: tile 0
    {
        short8 p8[2], q8[2], a8[2];
        loadPQ(0, p8, q8);
        buildA(p8, q8, a8);
        *(short8*)(&lA[0][wAo[0]]) = a8[0];
        *(short8*)(&lA[0][wAo[1]]) = a8[1];
        stageB(0, 0);
    }
    pipe_barrier();

    const int nt = K >> 5;  // 16
    int cur = 0;
    for (int t = 0; t < nt; ++t) {
        short8 p8[2], q8[2];
        if (t + 1 < nt) {
            loadPQ((t + 1) << 5, p8, q8);   // issue early; consumed after MFMA
            stageB(cur ^ 1, (t + 1) << 5);  // DMA, lands during MFMA
        }
        short8 av[4], bv[4];
#pragma unroll
        for (int i = 0; i < 4; ++i)
            av[i] = *(const short8*)(&lA[cur][(wm * 64 + i * 16 + l) * 32 + q * 8]);
#pragma unroll
        for (int j = 0; j < 4; ++j)
            bv[j] = *(const short8*)(&lB[cur][(wn * 64 + j * 16 + l) * 32 + q * 8]);
#pragma unroll
        for (int i = 0; i < 4; ++i)
#pragma unroll
            for (int j = 0; j < 4; ++j)
                acc[i][j] = __builtin_amdgcn_mfma_f32_16x16x32_bf16(av[i], bv[j], acc[i][j], 0, 0, 0);
        if (t + 1 < nt) {
            short8 a8[2];
            buildA(p8, q8, a8);
            *(short8*)(&lA[cur ^ 1][wAo[0]]) = a8[0];
            *(short8*)(&lA[cur ^ 1][wAo[1]]) = a8[1];
            pipe_barrier();
        }
        cur ^= 1;
    }

#pragma unroll
    for (int j = 0; j < 4; ++j) {
        const int colL = wn * 64 + j * 16 + l;
        const int col = n0 + colL;
        const float bb = bias[col];
        float psum = 0.f, psq = 0.f;
#pragma unroll
        for (int i = 0; i < 4; ++i) {
            const int g = (m0 >> 2) + wm * 16 + i * 4 + q;   // chunk-local node row
            float s0 = sigmoidf_(acc[i][j][0] + bb);
            float s1 = sigmoidf_(acc[i][j][1] + bb);
            float s2 = sigmoidf_(acc[i][j][2] + bb);
            float vm = (s0 + s1 + s2) * (1.f / 3.f);
            inf_[(size_t)g * 512 + 256 + col] = f2bu(vm);
            psum += vm; psq += vm * vm;
        }
        atomicAdd(&s_sum[colL], psum);
        atomicAdd(&s_sq[colL], psq);
    }
    __syncthreads();
    if (tid < 128) {
        atomicAdd(&ssum[n0 + tid], s_sum[tid]);
        atomicAdd(&ssq[n0 + tid], s_sq[tid]);
    }
}

extern "C" void kernel_launch(void* const* d_in, const int* in_sizes, int n_in,
                              void* d_out, int out_size, void* d_ws, size_t ws_size,
                              hipStream_t stream) {
    const float* x   = (const float*)d_in[0];
    const float* ng0 = (const float*)d_in[1];
    const float* nb0 = (const float*)d_in[2];
    const float* nW0 = (const float*)d_in[3];
    const float* nc0 = (const float*)d_in[4];
    const float* ng1 = (const float*)d_in[5];
    const float* nb1 = (const float*)d_in[6];
    const float* nW1 = (const float*)d_in[7];
    const float* nc1 = (const float*)d_in[8];
    const float* mg0 = (const float*)d_in[9];
    const float* mb0 = (const float*)d_in[10];
    const float* mW0 = (const float*)d_in[11];
    const float* mc0 = (const float*)d_in[12];
    const float* mg1 = (const float*)d_in[13];
    const float* mb1 = (const float*)d_in[14];
    const float* mW1 = (const float*)d_in[15];
    const float* mc1 = (const float*)d_in[16];
    const float* fg0 = (const float*)d_in[17];
    const float* fb0 = (const float*)d_in[18];
    const float* fW0 = (const float*)d_in[19];
    const float* fc0 = (const float*)d_in[20];
    const float* fg1 = (const float*)d_in[21];
    const float* fb1 = (const float*)d_in[22];
    const float* fW1 = (const float*)d_in[23];
    const float* fc1 = (const float*)d_in[24];

    char* ws = (char*)d_ws;
    const size_t MiB = 1024 * 1024;

    // chunk count for PQ: peak ws = 100 + 128/Cq MiB (x16 adds 32 MiB)
    int Cq = 1;
    while (Cq < 8 && (100 + 128 / Cq) * MiB > ws_size) Cq *= 2;
    const int G = 65536 / Cq;  // node rows per chunk (multiple of 32)

    // header [0,4MiB): stats (zeroed) + biases + folded weights
    float* stat = (float*)ws;
    float* sx_s   = stat + 0;     // 256
    float* sx_q   = stat + 256;   // 256
    float* shn_s  = stat + 512;   // 512
    float* shn_q  = stat + 1024;
    float* shm_s  = stat + 1536;
    float* shm_q  = stat + 2048;
    float* sif_s  = stat + 2560;
    float* sif_q  = stat + 3072;
    float* shf_s  = stat + 3584;
    float* shf_q  = stat + 4096;  // -> 4608
    float* biasPQ = stat + 4608;  // 1024, upper 512 stay zero
    // zeroed region ends at 5632 floats
    float* bias_n = stat + 5632;  // 512
    float* b1n    = stat + 6144;  // 256
    float* b1m    = stat + 6400;  // 256
    float* b0f    = stat + 6656;  // 512
    float* b1f    = stat + 7168;  // 256

    unsigned short* An  = (unsigned short*)(ws + 256 * 1024);  // [512][256]
    unsigned short* Btm = An + 512 * 256;                      // [1024][256]
    unsigned short* A1n = Btm + 1024 * 256;                    // [256][512]
    unsigned short* A1m = A1n + 256 * 512;                     // [256][512]
    unsigned short* A0f = A1m + 256 * 512;                     // [512][512]
    unsigned short* A1f = A0f + 512 * 512;                     // [256][512]

    // [4,68): hn (bf16, live gemm1..gemm2n) -> hf (bf16, live gemm3..gemm4)
    // [68, 68+128/Cq): PQ chunk buffer
    // [68+128/Cq, +32): x16 bf16 [65536][256]
    unsigned short* hn    = (unsigned short*)(ws + 4 * MiB);
    unsigned short* hf    = (unsigned short*)(ws + 4 * MiB);
    unsigned short* PQbuf = (unsigned short*)(ws + 68 * MiB);
    unsigned short* x16   = (unsigned short*)(ws + (68 + 128 / Cq) * MiB);
    unsigned short* inf   = (unsigned short*)d_out;  // [65536,512] bf16, dead before gemm4

    const float inv1 = 1.f / 65536.f;
    const float invM = 1.f / 196608.f;

    // zero stats + biasPQ (5632 floats = 1408 float4)
    k_zero4<<<6, 256, 0, stream>>>((float4*)stat, 1408);

    // x -> bf16 + column stats (fused)
    k_xcvt<<<1024, 256, 0, stream>>>(x, x16, sx_s, sx_q);

    // fold BN0 (msg BN0 stats == node BN0 stats: each node appears exactly
    // 3x as src and 3x as dst across the 12 ordered pairs)
    k_fold<<<512, 256, 0, stream>>>(nW0, ng0, nb0, sx_s, sx_q, nc0, inv1, 512, 256, An, bias_n, 0);
    k_fold<<<512, 256, 0, stream>>>(mW0, mg0, mb0, sx_s, sx_q, mc0, inv1, 512, 256, Btm, biasPQ, 0);
    k_fold<<<512, 256, 0, stream>>>(mW0 + 256 * 512, mg0 + 256, mb0 + 256, sx_s, sx_q, nullptr,
                                    inv1, 512, 256, Btm + 512 * 256, biasPQ, 1);

    // h_n = relu(x16 @ An + bias_n), BN1_n stats
    k_gemm<1><<<dim3(4, 512), 256, 0, stream>>>(x16, 256, An, hn, 512, bias_n, shn_s, shn_q, 256);

    // PQ chunks: PQ = x16_chunk @ [Amt|Amb] + [bias_m|0]; accumulate BN1_m stats
    for (int c = 0; c < Cq; ++c) {
        k_gemm<5><<<dim3(8, 512 / Cq), 256, 0, stream>>>(
            x16 + (size_t)c * G * 256, 256, Btm, PQbuf, 1024, biasPQ, nullptr, nullptr, 256);
        k_msgstats2<<<1024 / Cq, 256, 0, stream>>>(PQbuf, shm_s, shm_q);
    }

    // fold BN1
    k_fold<<<256, 256, 0, stream>>>(nW1, ng1, nb1, shn_s, shn_q, nc1, inv1, 256, 512, A1n, b1n, 0);
    k_fold<<<256, 256, 0, stream>>>(mW1, mg1, mb1, shm_s, shm_q, mc1, invM, 256, 512, A1m, b1m, 0);

    // x_node = sigmoid(hn @ A1n + b1n) -> in_f[:,0:256] (in d_out), f-BN0 stats
    k_gemm<2><<<dim3(2, 512), 256, 0, stream>>>(hn, 512, A1n, inf, 512, b1n, sif_s, sif_q, 512);

    // x_agg: padded msg GEMM -> in_f[:,256:512] bf16 + f-BN0 stats (cols 256..511)
    for (int c = 0; c < Cq; ++c) {
        if (Cq > 1)  // recompute PQ chunk (Cq==1 kept the full PQ)
            k_gemm<5><<<dim3(8, 512 / Cq), 256, 0, stream>>>(
                x16 + (size_t)c * G * 256, 256, Btm, PQbuf, 1024, biasPQ, nullptr, nullptr, 256);
        k_gemm_msg3<<<dim3(2, G / 32), 256, 0, stream>>>(
            PQbuf, A1m, inf + (size_t)c * G * 512, b1m, sif_s + 256, sif_q + 256);
    }

    // final MLP
    k_fold<<<512, 256, 0, stream>>>(fW0, fg0, fb0, sif_s, sif_q, fc0, inv1, 512, 512, A0f, b0f, 0);
    k_gemm<1><<<dim3(4, 512), 256, 0, stream>>>(inf, 512, A0f, hf, 512, b0f, shf_s, shf_q, 512);
    k_fold<<<256, 256, 0, stream>>>(fW1, fg1, fb1, shf_s, shf_q, fc1, inv1, 256, 512, A1f, b1f, 0);
    k_gemm<4><<<dim3(2, 512), 256, 0, stream>>>(hf, 512, A1f, d_out, 256, b1f, nullptr, nullptr, 512);

    (void)in_sizes; (void)n_in; (void)out_size;
}

// Round 4
// 693.672 us; speedup vs baseline: 1.4285x; 1.0070x over previous
//
#include <hip/hip_runtime.h>

// GNNLayer: 3 MLPs (node/message/final). BN folded into GEMM weights.
// bf16 storage, fp32 MFMA accumulation, fp32 stats.
// Round 4:
//  - k_gemm: counted-vmcnt 3-buffer pipeline (vmcnt(4) steady state, never 0
//    in main loop; single barrier per K-step; stage issued after barrier).
//  - k_gemm_msg3: A-build via paired bf16 unpack + v_cvt_pk_bf16_f32 repack
//    (~2x fewer VALU ops); structure unchanged (2-buffer, VALU-bound).

typedef __attribute__((ext_vector_type(8))) short short8;
typedef __attribute__((ext_vector_type(4))) float f32x4;
typedef __attribute__((ext_vector_type(4))) unsigned int u32x4;

__device__ __forceinline__ unsigned short f2bu(float f) {
    unsigned int x = __float_as_uint(f);
    x += 0x7fffu + ((x >> 16) & 1u);
    return (unsigned short)(x >> 16);
}
__device__ __forceinline__ float b2f(unsigned short u) {
    return __uint_as_float(((unsigned int)u) << 16);
}
__device__ __forceinline__ float sigmoidf_(float v) {
    return 1.0f / (1.0f + __expf(-v));
}

// async global->LDS DMA, 16 B per lane; LDS dest = wave-uniform base + lane*16
__device__ __forceinline__ void gld16(const void* g, void* l) {
    __builtin_amdgcn_global_load_lds(
        (const __attribute__((address_space(1))) void*)g,
        (__attribute__((address_space(3))) void*)l, 16, 0, 0);
}

// pipeline barrier (msg3): drain DMA + LDS ops, raw barrier
__device__ __forceinline__ void pipe_barrier() {
    asm volatile("s_waitcnt vmcnt(0) lgkmcnt(0)" ::: "memory");
    __builtin_amdgcn_s_barrier();
    __builtin_amdgcn_sched_barrier(0);
}

__global__ __launch_bounds__(256) void k_zero4(float4* p, int n4) {
    int i = blockIdx.x * 256 + threadIdx.x;
    if (i < n4) p[i] = make_float4(0.f, 0.f, 0.f, 0.f);
}

// x fp32 -> bf16 copy + per-feature sum/sumsq (fused)
__global__ __launch_bounds__(256) void k_xcvt(const float* __restrict__ x,
                                              unsigned short* __restrict__ x16,
                                              float* __restrict__ ssum,
                                              float* __restrict__ ssq) {
    const int c = threadIdx.x;
    const int r0 = blockIdx.x * 64;
    float s = 0.f, q = 0.f;
    for (int r = r0; r < r0 + 64; ++r) {
        float v = x[(size_t)r * 256 + c];
        x16[(size_t)r * 256 + c] = f2bu(v);
        s += v; q += v * v;
    }
    atomicAdd(&ssum[c], s);
    atomicAdd(&ssq[c], q);
}

// fold BN into weights: Bt[j][k] = s_k*W[k][j] (bf16, [N][K]);
// bias[j] (+)= c[j] + sum_k t_k*W[k][j]. One block per output column j.
__global__ __launch_bounds__(256) void k_fold(const float* __restrict__ W,      // [Kc][N]
                                              const float* __restrict__ gamma,
                                              const float* __restrict__ beta,
                                              const float* __restrict__ ssum,
                                              const float* __restrict__ ssq,
                                              const float* __restrict__ cvec,   // [N] or null
                                              float inv_count, int N, int Kc,
                                              unsigned short* __restrict__ Bt,  // [N][Kc]
                                              float* __restrict__ bias, int bias_add) {
    const int j = blockIdx.x;
    const int t = threadIdx.x;
    float part = 0.f;
    for (int k = t; k < Kc; k += 256) {
        float mu  = ssum[k] * inv_count;
        float var = ssq[k] * inv_count - mu * mu;
        float s   = gamma[k] * rsqrtf(var + 1e-5f);
        float tt  = beta[k] - mu * s;
        float w   = W[(size_t)k * N + j];
        Bt[(size_t)j * Kc + k] = f2bu(s * w);
        part += tt * w;
    }
    __shared__ float red[256];
    red[t] = part;
    __syncthreads();
    for (int s2 = 128; s2 > 0; s2 >>= 1) {
        if (t < s2) red[t] += red[t + s2];
        __syncthreads();
    }
    if (t == 0) {
        if (bias_add) atomicAdd(&bias[j], red[0]);
        else bias[j] = red[0] + cvec[j];
    }
}

// stats of h_m = relu(P+Q) over one PQ chunk, vectorized (short8 loads).
__global__ __launch_bounds__(256) void k_msgstats2(const unsigned short* __restrict__ PQ,
                                                   float* __restrict__ ssum,
                                                   float* __restrict__ ssq) {
    const int cg = threadIdx.x & 63;        // 64 groups x 8 cols = 512
    const int sub = threadIdx.x >> 6;       // 0..3
    const int b0 = blockIdx.x * 16 + sub * 4;
    float s[8] = {}, qq[8] = {};
    for (int g = 0; g < 4; ++g) {
        const int b = b0 + g;
        float Pf[4][8], Qf[4][8];
#pragma unroll
        for (int n = 0; n < 4; ++n) {
            short8 p8 = *(const short8*)(PQ + (size_t)(b * 4 + n) * 1024 + cg * 8);
            short8 q8 = *(const short8*)(PQ + (size_t)(b * 4 + n) * 1024 + 512 + cg * 8);
#pragma unroll
            for (int e = 0; e < 8; ++e) {
                Pf[n][e] = b2f((unsigned short)p8[e]);
                Qf[n][e] = b2f((unsigned short)q8[e]);
            }
        }
#pragma unroll
        for (int si = 0; si < 4; ++si)
#pragma unroll
            for (int di = 0; di < 4; ++di) {
                if (si == di) continue;
#pragma unroll
                for (int e = 0; e < 8; ++e) {
                    float v = fmaxf(Pf[si][e] + Qf[di][e], 0.f);
                    s[e] += v; qq[e] += v * v;
                }
            }
    }
    __shared__ float sS[512], sQ[512];
    sS[threadIdx.x] = 0.f; sS[threadIdx.x + 256] = 0.f;
    sQ[threadIdx.x] = 0.f; sQ[threadIdx.x + 256] = 0.f;
    __syncthreads();
#pragma unroll
    for (int e = 0; e < 8; ++e) {
        atomicAdd(&sS[cg * 8 + e], s[e]);
        atomicAdd(&sQ[cg * 8 + e], qq[e]);
    }
    __syncthreads();
    for (int cidx = threadIdx.x; cidx < 512; cidx += 256) {
        atomicAdd(&ssum[cidx], sS[cidx]);
        atomicAdd(&ssq[cidx], sQ[cidx]);
    }
}

// 128x128-tile bf16 MFMA GEMM, A [M][lda] bf16, Bt [N][K] bf16.
// global_load_lds width=16 staging, 3-buffer counted-vmcnt pipeline:
// steady state waits vmcnt(4) (next tile's 4 DMAs stay in flight), one
// barrier per K-step, stage(t+2) issued after the barrier.
// EPI: 1 bias+relu+stats bf16; 2 bias+sigmoid+stats bf16; 4 bias+sigmoid f32; 5 bias bf16
template <int EPI>
__global__ __launch_bounds__(256) void k_gemm(const unsigned short* __restrict__ A, int lda,
                                              const unsigned short* __restrict__ Bt,
                                              void* __restrict__ C, int ldc,
                                              const float* __restrict__ bias,
                                              float* __restrict__ ssum, float* __restrict__ ssq,
                                              int K) {
    const int n0 = blockIdx.x * 128;
    const int m0 = blockIdx.y * 128;
    const int tid = threadIdx.x;
    const int w = tid >> 6;
    const int lane = tid & 63;
    const int q = lane >> 4;
    const int l = lane & 15;
    const int wm = w >> 1;
    const int wn = w & 1;

    __shared__ __align__(16) unsigned short lA[3][128 * 32];  // [m][k]
    __shared__ __align__(16) unsigned short lB[3][128 * 32];  // [n][k]
    __shared__ float s_sum[128];
    __shared__ float s_sq[128];

    if ((EPI == 1 || EPI == 2) && tid < 128) { s_sum[tid] = 0.f; s_sq[tid] = 0.f; }

    f32x4 acc[4][4] = {};

    const int rsub = tid >> 2;          // 0..63
    const int ksub = (tid & 3) * 8;     // 0,8,16,24
    const unsigned short* gA = A + (size_t)(m0 + rsub) * lda + ksub;
    const unsigned short* gB = Bt + (size_t)(n0 + rsub) * K + ksub;
    const unsigned wofs = (unsigned)(tid >> 6) * 1024;  // wave LDS base, bytes

    auto stage = [&](int buf, int k0) {   // 4 DMA ops per wave
        char* la = (char*)lA[buf] + wofs;
        char* lb = (char*)lB[buf] + wofs;
        gld16(gA + k0, la);
        gld16(gA + (size_t)64 * lda + k0, la + 4096);
        gld16(gB + k0, lb);
        gld16(gB + (size_t)64 * K + k0, lb + 4096);
    };

    const int nt = K >> 5;
    stage(0, 0);
    if (nt > 1) stage(1, 32);

    int cur = 0;
    for (int t = 0; t < nt; ++t) {
        // tile t's 4 DMAs done; tile t+1's (if any) may remain in flight
        if (t + 1 < nt) { asm volatile("s_waitcnt vmcnt(4)" ::: "memory"); }
        else            { asm volatile("s_waitcnt vmcnt(0)" ::: "memory"); }
        __builtin_amdgcn_s_barrier();
        __builtin_amdgcn_sched_barrier(0);
        if (t + 2 < nt) {
            int b2 = cur + 2; if (b2 >= 3) b2 -= 3;
            stage(b2, (t + 2) << 5);   // overwrites buf t-1: safe, all reads done
        }
        short8 av[4], bv[4];
#pragma unroll
        for (int i = 0; i < 4; ++i)
            av[i] = *(const short8*)(&lA[cur][(wm * 64 + i * 16 + l) * 32 + q * 8]);
#pragma unroll
        for (int j = 0; j < 4; ++j)
            bv[j] = *(const short8*)(&lB[cur][(wn * 64 + j * 16 + l) * 32 + q * 8]);
#pragma unroll
        for (int i = 0; i < 4; ++i)
#pragma unroll
            for (int j = 0; j < 4; ++j)
                acc[i][j] = __builtin_amdgcn_mfma_f32_16x16x32_bf16(av[i], bv[j], acc[i][j], 0, 0, 0);
        cur = (cur == 2) ? 0 : cur + 1;
    }

#pragma unroll
    for (int j = 0; j < 4; ++j) {
        const int colL = wn * 64 + j * 16 + l;
        const int col = n0 + colL;
        const float bb = bias[col];
        float psum = 0.f, psq = 0.f;
#pragma unroll
        for (int i = 0; i < 4; ++i) {
            const int rowL = wm * 64 + i * 16 + q * 4;
#pragma unroll
            for (int r = 0; r < 4; ++r) {
                float v = acc[i][j][r] + bb;
                if (EPI == 1) v = fmaxf(v, 0.f);
                if (EPI == 2 || EPI == 4) v = sigmoidf_(v);
                const size_t off = (size_t)(m0 + rowL + r) * ldc + col;
                if (EPI == 4) ((float*)C)[off] = v;
                else ((unsigned short*)C)[off] = f2bu(v);
                psum += v; psq += v * v;
            }
        }
        if (EPI == 1 || EPI == 2) {
            atomicAdd(&s_sum[colL], psum);
            atomicAdd(&s_sq[colL], psq);
        }
    }
    if (EPI == 1 || EPI == 2) {
        __syncthreads();
        if (tid < 128) {
            atomicAdd(&ssum[n0 + tid], s_sum[tid]);
            atomicAdd(&ssq[n0 + tid], s_sq[tid]);
        }
    }
}

// Fused message GEMM + in-register mean + bf16 store + column stats.
// Padded M: row m = 4*node + slot (slot 0..2 = messages, slot 3 = zero pad).
// A-build: paired bf16 unpack + v_cvt_pk_bf16_f32 repack (RNE), ~2x fewer
// VALU ops than scalar f2bu path. 2-buffer pipeline, B via DMA.
__global__ __launch_bounds__(256) void k_gemm_msg3(const unsigned short* __restrict__ PQ,  // [G][1024] chunk-local
                                                   const unsigned short* __restrict__ Bt,  // A1m [256][512]
                                                   unsigned short* __restrict__ inf_,      // chunk-offset, [G][512] bf16
                                                   const float* __restrict__ bias,         // b1m [256]
                                                   float* __restrict__ ssum,               // sif_s+256
                                                   float* __restrict__ ssq) {              // sif_q+256
    const int K = 512;
    const int n0 = blockIdx.x * 128;
    const int m0 = blockIdx.y * 128;          // padded chunk-local msg row base
    const int tid = threadIdx.x;
    const int w = tid >> 6;
    const int lane = tid & 63;
    const int q = lane >> 4;
    const int l = lane & 15;
    const int wm = w >> 1;
    const int wn = w & 1;

    __shared__ __align__(16) unsigned short lA[2][128 * 32];
    __shared__ __align__(16) unsigned short lB[2][128 * 32];
    __shared__ float s_sum[128];
    __shared__ float s_sq[128];

    if (tid < 128) { s_sum[tid] = 0.f; s_sq[tid] = 0.f; }

    f32x4 acc[4][4] = {};

    const int rsub = tid >> 2;          // 0..63
    const int ksub = (tid & 3) * 8;     // 0,8,16,24
    unsigned aP[2], aQ[2], wAo[2];
    bool pad[2];
#pragma unroll
    for (int t = 0; t < 2; ++t) {
        int row = m0 + t * 64 + rsub;    // padded chunk-local msg row
        int node = row >> 2;             // chunk-local node
        int slot = row & 3;
        pad[t] = (slot == 3);
        int si = node & 3;
        int di = slot + (slot >= si ? 1 : 0);
        aP[t] = (unsigned)node * 1024 + ksub;
        aQ[t] = (unsigned)(node - si + di) * 1024 + 512 + ksub;
        wAo[t] = (unsigned)((t * 64 + rsub) * 32 + ksub);
    }
    const unsigned short* gB = Bt + (size_t)(n0 + rsub) * K + ksub;
    const unsigned wofs = (unsigned)(tid >> 6) * 1024;

    auto loadPQ = [&](int k0, short8 p8[2], short8 q8[2]) {
#pragma unroll
        for (int t = 0; t < 2; ++t) {
            if (!pad[t]) {
                p8[t] = *(const short8*)(PQ + aP[t] + k0);
                q8[t] = *(const short8*)(PQ + aQ[t] + k0);
            }
        }
    };
    auto buildA = [&](const short8 p8[2], const short8 q8[2], short8 a8[2]) {
#pragma unroll
        for (int t = 0; t < 2; ++t) {
            if (!pad[t]) {
                u32x4 pu = __builtin_bit_cast(u32x4, p8[t]);
                u32x4 qu = __builtin_bit_cast(u32x4, q8[t]);
                u32x4 ou;
#pragma unroll
                for (int i = 0; i < 4; ++i) {
                    float pl = __uint_as_float(pu[i] << 16);
                    float ph = __uint_as_float(pu[i] & 0xffff0000u);
                    float ql = __uint_as_float(qu[i] << 16);
                    float qh = __uint_as_float(qu[i] & 0xffff0000u);
                    float sl = fmaxf(pl + ql, 0.f);
                    float sh = fmaxf(ph + qh, 0.f);
                    unsigned r;
                    asm("v_cvt_pk_bf16_f32 %0, %1, %2" : "=v"(r) : "v"(sl), "v"(sh));
                    ou[i] = r;
                }
                a8[t] = __builtin_bit_cast(short8, ou);
            } else {
                short8 z = {};
                a8[t] = z;
            }
        }
    };
    auto stageB = [&](int buf, int k0) {
        char* lb = (char*)lB[buf] + wofs;
        gld16(gB + k0, lb);
        gld16(gB + (size_t)64 * K + k0, lb + 4096);
    };

    // prologue: tile 0
    {
        short8 p8[2], q8[2], a8[2];
        loadPQ(0, p8, q8);
        buildA(p8, q8, a8);
        *(short8*)(&lA[0][wAo[0]]) = a8[0];
        *(short8*)(&lA[0][wAo[1]]) = a8[1];
        stageB(0, 0);
    }
    pipe_barrier();

    const int nt = K >> 5;  // 16
    int cur = 0;
    for (int t = 0; t < nt; ++t) {
        short8 p8[2], q8[2];
        if (t + 1 < nt) {
            loadPQ((t + 1) << 5, p8, q8);   // issue early; consumed after MFMA
            stageB(cur ^ 1, (t + 1) << 5);  // DMA, lands during MFMA
        }
        short8 av[4], bv[4];
#pragma unroll
        for (int i = 0; i < 4; ++i)
            av[i] = *(const short8*)(&lA[cur][(wm * 64 + i * 16 + l) * 32 + q * 8]);
#pragma unroll
        for (int j = 0; j < 4; ++j)
            bv[j] = *(const short8*)(&lB[cur][(wn * 64 + j * 16 + l) * 32 + q * 8]);
#pragma unroll
        for (int i = 0; i < 4; ++i)
#pragma unroll
            for (int j = 0; j < 4; ++j)
                acc[i][j] = __builtin_amdgcn_mfma_f32_16x16x32_bf16(av[i], bv[j], acc[i][j], 0, 0, 0);
        if (t + 1 < nt) {
            short8 a8[2];
            buildA(p8, q8, a8);
            *(short8*)(&lA[cur ^ 1][wAo[0]]) = a8[0];
            *(short8*)(&lA[cur ^ 1][wAo[1]]) = a8[1];
            pipe_barrier();
        }
        cur ^= 1;
    }

#pragma unroll
    for (int j = 0; j < 4; ++j) {
        const int colL = wn * 64 + j * 16 + l;
        const int col = n0 + colL;
        const float bb = bias[col];
        float psum = 0.f, psq = 0.f;
#pragma unroll
        for (int i = 0; i < 4; ++i) {
            const int g = (m0 >> 2) + wm * 16 + i * 4 + q;   // chunk-local node row
            float s0 = sigmoidf_(acc[i][j][0] + bb);
            float s1 = sigmoidf_(acc[i][j][1] + bb);
            float s2 = sigmoidf_(acc[i][j][2] + bb);
            float vm = (s0 + s1 + s2) * (1.f / 3.f);
            inf_[(size_t)g * 512 + 256 + col] = f2bu(vm);
            psum += vm; psq += vm * vm;
        }
        atomicAdd(&s_sum[colL], psum);
        atomicAdd(&s_sq[colL], psq);
    }
    __syncthreads();
    if (tid < 128) {
        atomicAdd(&ssum[n0 + tid], s_sum[tid]);
        atomicAdd(&ssq[n0 + tid], s_sq[tid]);
    }
}

extern "C" void kernel_launch(void* const* d_in, const int* in_sizes, int n_in,
                              void* d_out, int out_size, void* d_ws, size_t ws_size,
                              hipStream_t stream) {
    const float* x   = (const float*)d_in[0];
    const float* ng0 = (const float*)d_in[1];
    const float* nb0 = (const float*)d_in[2];
    const float* nW0 = (const float*)d_in[3];
    const float* nc0 = (const float*)d_in[4];
    const float* ng1 = (const float*)d_in[5];
    const float* nb1 = (const float*)d_in[6];
    const float* nW1 = (const float*)d_in[7];
    const float* nc1 = (const float*)d_in[8];
    const float* mg0 = (const float*)d_in[9];
    const float* mb0 = (const float*)d_in[10];
    const float* mW0 = (const float*)d_in[11];
    const float* mc0 = (const float*)d_in[12];
    const float* mg1 = (const float*)d_in[13];
    const float* mb1 = (const float*)d_in[14];
    const float* mW1 = (const float*)d_in[15];
    const float* mc1 = (const float*)d_in[16];
    const float* fg0 = (const float*)d_in[17];
    const float* fb0 = (const float*)d_in[18];
    const float* fW0 = (const float*)d_in[19];
    const float* fc0 = (const float*)d_in[20];
    const float* fg1 = (const float*)d_in[21];
    const float* fb1 = (const float*)d_in[22];
    const float* fW1 = (const float*)d_in[23];
    const float* fc1 = (const float*)d_in[24];

    char* ws = (char*)d_ws;
    const size_t MiB = 1024 * 1024;

    // chunk count for PQ: peak ws = 100 + 128/Cq MiB (x16 adds 32 MiB)
    int Cq = 1;
    while (Cq < 8 && (100 + 128 / Cq) * MiB > ws_size) Cq *= 2;
    const int G = 65536 / Cq;  // node rows per chunk (multiple of 32)

    // header [0,4MiB): stats (zeroed) + biases + folded weights
    float* stat = (float*)ws;
    float* sx_s   = stat + 0;     // 256
    float* sx_q   = stat + 256;   // 256
    float* shn_s  = stat + 512;   // 512
    float* shn_q  = stat + 1024;
    float* shm_s  = stat + 1536;
    float* shm_q  = stat + 2048;
    float* sif_s  = stat + 2560;
    float* sif_q  = stat + 3072;
    float* shf_s  = stat + 3584;
    float* shf_q  = stat + 4096;  // -> 4608
    float* biasPQ = stat + 4608;  // 1024, upper 512 stay zero
    // zeroed region ends at 5632 floats
    float* bias_n = stat + 5632;  // 512
    float* b1n    = stat + 6144;  // 256
    float* b1m    = stat + 6400;  // 256
    float* b0f    = stat + 6656;  // 512
    float* b1f    = stat + 7168;  // 256

    unsigned short* An  = (unsigned short*)(ws + 256 * 1024);  // [512][256]
    unsigned short* Btm = An + 512 * 256;                      // [1024][256]
    unsigned short* A1n = Btm + 1024 * 256;                    // [256][512]
    unsigned short* A1m = A1n + 256 * 512;                     // [256][512]
    unsigned short* A0f = A1m + 256 * 512;                     // [512][512]
    unsigned short* A1f = A0f + 512 * 512;                     // [256][512]

    // [4,68): hn (bf16, live gemm1..gemm2n) -> hf (bf16, live gemm3..gemm4)
    // [68, 68+128/Cq): PQ chunk buffer
    // [68+128/Cq, +32): x16 bf16 [65536][256]
    unsigned short* hn    = (unsigned short*)(ws + 4 * MiB);
    unsigned short* hf    = (unsigned short*)(ws + 4 * MiB);
    unsigned short* PQbuf = (unsigned short*)(ws + 68 * MiB);
    unsigned short* x16   = (unsigned short*)(ws + (68 + 128 / Cq) * MiB);
    unsigned short* inf   = (unsigned short*)d_out;  // [65536,512] bf16, dead before gemm4

    const float inv1 = 1.f / 65536.f;
    const float invM = 1.f / 196608.f;

    // zero stats + biasPQ (5632 floats = 1408 float4)
    k_zero4<<<6, 256, 0, stream>>>((float4*)stat, 1408);

    // x -> bf16 + column stats (fused)
    k_xcvt<<<1024, 256, 0, stream>>>(x, x16, sx_s, sx_q);

    // fold BN0 (msg BN0 stats == node BN0 stats: each node appears exactly
    // 3x as src and 3x as dst across the 12 ordered pairs)
    k_fold<<<512, 256, 0, stream>>>(nW0, ng0, nb0, sx_s, sx_q, nc0, inv1, 512, 256, An, bias_n, 0);
    k_fold<<<512, 256, 0, stream>>>(mW0, mg0, mb0, sx_s, sx_q, mc0, inv1, 512, 256, Btm, biasPQ, 0);
    k_fold<<<512, 256, 0, stream>>>(mW0 + 256 * 512, mg0 + 256, mb0 + 256, sx_s, sx_q, nullptr,
                                    inv1, 512, 256, Btm + 512 * 256, biasPQ, 1);

    // h_n = relu(x16 @ An + bias_n), BN1_n stats
    k_gemm<1><<<dim3(4, 512), 256, 0, stream>>>(x16, 256, An, hn, 512, bias_n, shn_s, shn_q, 256);

    // PQ chunks: PQ = x16_chunk @ [Amt|Amb] + [bias_m|0]; accumulate BN1_m stats
    for (int c = 0; c < Cq; ++c) {
        k_gemm<5><<<dim3(8, 512 / Cq), 256, 0, stream>>>(
            x16 + (size_t)c * G * 256, 256, Btm, PQbuf, 1024, biasPQ, nullptr, nullptr, 256);
        k_msgstats2<<<1024 / Cq, 256, 0, stream>>>(PQbuf, shm_s, shm_q);
    }

    // fold BN1
    k_fold<<<256, 256, 0, stream>>>(nW1, ng1, nb1, shn_s, shn_q, nc1, inv1, 256, 512, A1n, b1n, 0);
    k_fold<<<256, 256, 0, stream>>>(mW1, mg1, mb1, shm_s, shm_q, mc1, invM, 256, 512, A1m, b1m, 0);

    // x_node = sigmoid(hn @ A1n + b1n) -> in_f[:,0:256] (in d_out), f-BN0 stats
    k_gemm<2><<<dim3(2, 512), 256, 0, stream>>>(hn, 512, A1n, inf, 512, b1n, sif_s, sif_q, 512);

    // x_agg: padded msg GEMM -> in_f[:,256:512] bf16 + f-BN0 stats (cols 256..511)
    for (int c = 0; c < Cq; ++c) {
        if (Cq > 1)  // recompute PQ chunk (Cq==1 kept the full PQ)
            k_gemm<5><<<dim3(8, 512 / Cq), 256, 0, stream>>>(
                x16 + (size_t)c * G * 256, 256, Btm, PQbuf, 1024, biasPQ, nullptr, nullptr, 256);
        k_gemm_msg3<<<dim3(2, G / 32), 256, 0, stream>>>(
            PQbuf, A1m, inf + (size_t)c * G * 512, b1m, sif_s + 256, sif_q + 256);
    }

    // final MLP
    k_fold<<<512, 256, 0, stream>>>(fW0, fg0, fb0, sif_s, sif_q, fc0, inv1, 512, 512, A0f, b0f, 0);
    k_gemm<1><<<dim3(4, 512), 256, 0, stream>>>(inf, 512, A0f, hf, 512, b0f, shf_s, shf_q, 512);
    k_fold<<<256, 256, 0, stream>>>(fW1, fg1, fb1, shf_s, shf_q, fc1, inv1, 256, 512, A1f, b1f, 0);
    k_gemm<4><<<dim3(2, 512), 256, 0, stream>>>(hf, 512, A1f, d_out, 256, b1f, nullptr, nullptr, 512);

    (void)in_sizes; (void)n_in; (void)out_size;
}

// Round 5
// 688.992 us; speedup vs baseline: 1.4382x; 1.0068x over previous
//
#include <hip/hip_runtime.h>

// GNNLayer: 3 MLPs (node/message/final). BN folded into GEMM weights.
// bf16 storage, fp32 MFMA accumulation, fp32 stats.
// Round 5: k_gemm_msg4 = 128x256 single-n-block tile (grid.x=1). The
// expensive on-the-fly A-build (relu(P+Q), VALU-bound) now runs ONCE per
// output tile instead of twice (was rebuilt per 128-col block). acc[4][8],
// 4 waves, B (A1m, L2-resident) staged 256 rows/step via DMA.
// Plain k_gemm keeps the 3-buffer counted-vmcnt pipeline (neutral, kept).

typedef __attribute__((ext_vector_type(8))) short short8;
typedef __attribute__((ext_vector_type(4))) float f32x4;
typedef __attribute__((ext_vector_type(4))) unsigned int u32x4;

__device__ __forceinline__ unsigned short f2bu(float f) {
    unsigned int x = __float_as_uint(f);
    x += 0x7fffu + ((x >> 16) & 1u);
    return (unsigned short)(x >> 16);
}
__device__ __forceinline__ float b2f(unsigned short u) {
    return __uint_as_float(((unsigned int)u) << 16);
}
__device__ __forceinline__ float sigmoidf_(float v) {
    return 1.0f / (1.0f + __expf(-v));
}

// async global->LDS DMA, 16 B per lane; LDS dest = wave-uniform base + lane*16
__device__ __forceinline__ void gld16(const void* g, void* l) {
    __builtin_amdgcn_global_load_lds(
        (const __attribute__((address_space(1))) void*)g,
        (__attribute__((address_space(3))) void*)l, 16, 0, 0);
}

// pipeline barrier: drain DMA + LDS ops, raw barrier
__device__ __forceinline__ void pipe_barrier() {
    asm volatile("s_waitcnt vmcnt(0) lgkmcnt(0)" ::: "memory");
    __builtin_amdgcn_s_barrier();
    __builtin_amdgcn_sched_barrier(0);
}

__global__ __launch_bounds__(256) void k_zero4(float4* p, int n4) {
    int i = blockIdx.x * 256 + threadIdx.x;
    if (i < n4) p[i] = make_float4(0.f, 0.f, 0.f, 0.f);
}

// x fp32 -> bf16 copy + per-feature sum/sumsq (fused)
__global__ __launch_bounds__(256) void k_xcvt(const float* __restrict__ x,
                                              unsigned short* __restrict__ x16,
                                              float* __restrict__ ssum,
                                              float* __restrict__ ssq) {
    const int c = threadIdx.x;
    const int r0 = blockIdx.x * 64;
    float s = 0.f, q = 0.f;
    for (int r = r0; r < r0 + 64; ++r) {
        float v = x[(size_t)r * 256 + c];
        x16[(size_t)r * 256 + c] = f2bu(v);
        s += v; q += v * v;
    }
    atomicAdd(&ssum[c], s);
    atomicAdd(&ssq[c], q);
}

// fold BN into weights: Bt[j][k] = s_k*W[k][j] (bf16, [N][K]);
// bias[j] (+)= c[j] + sum_k t_k*W[k][j]. One block per output column j.
__global__ __launch_bounds__(256) void k_fold(const float* __restrict__ W,      // [Kc][N]
                                              const float* __restrict__ gamma,
                                              const float* __restrict__ beta,
                                              const float* __restrict__ ssum,
                                              const float* __restrict__ ssq,
                                              const float* __restrict__ cvec,   // [N] or null
                                              float inv_count, int N, int Kc,
                                              unsigned short* __restrict__ Bt,  // [N][Kc]
                                              float* __restrict__ bias, int bias_add) {
    const int j = blockIdx.x;
    const int t = threadIdx.x;
    float part = 0.f;
    for (int k = t; k < Kc; k += 256) {
        float mu  = ssum[k] * inv_count;
        float var = ssq[k] * inv_count - mu * mu;
        float s   = gamma[k] * rsqrtf(var + 1e-5f);
        float tt  = beta[k] - mu * s;
        float w   = W[(size_t)k * N + j];
        Bt[(size_t)j * Kc + k] = f2bu(s * w);
        part += tt * w;
    }
    __shared__ float red[256];
    red[t] = part;
    __syncthreads();
    for (int s2 = 128; s2 > 0; s2 >>= 1) {
        if (t < s2) red[t] += red[t + s2];
        __syncthreads();
    }
    if (t == 0) {
        if (bias_add) atomicAdd(&bias[j], red[0]);
        else bias[j] = red[0] + cvec[j];
    }
}

// stats of h_m = relu(P+Q) over one PQ chunk, vectorized (short8 loads).
__global__ __launch_bounds__(256) void k_msgstats2(const unsigned short* __restrict__ PQ,
                                                   float* __restrict__ ssum,
                                                   float* __restrict__ ssq) {
    const int cg = threadIdx.x & 63;        // 64 groups x 8 cols = 512
    const int sub = threadIdx.x >> 6;       // 0..3
    const int b0 = blockIdx.x * 16 + sub * 4;
    float s[8] = {}, qq[8] = {};
    for (int g = 0; g < 4; ++g) {
        const int b = b0 + g;
        float Pf[4][8], Qf[4][8];
#pragma unroll
        for (int n = 0; n < 4; ++n) {
            short8 p8 = *(const short8*)(PQ + (size_t)(b * 4 + n) * 1024 + cg * 8);
            short8 q8 = *(const short8*)(PQ + (size_t)(b * 4 + n) * 1024 + 512 + cg * 8);
#pragma unroll
            for (int e = 0; e < 8; ++e) {
                Pf[n][e] = b2f((unsigned short)p8[e]);
                Qf[n][e] = b2f((unsigned short)q8[e]);
            }
        }
#pragma unroll
        for (int si = 0; si < 4; ++si)
#pragma unroll
            for (int di = 0; di < 4; ++di) {
                if (si == di) continue;
#pragma unroll
                for (int e = 0; e < 8; ++e) {
                    float v = fmaxf(Pf[si][e] + Qf[di][e], 0.f);
                    s[e] += v; qq[e] += v * v;
                }
            }
    }
    __shared__ float sS[512], sQ[512];
    sS[threadIdx.x] = 0.f; sS[threadIdx.x + 256] = 0.f;
    sQ[threadIdx.x] = 0.f; sQ[threadIdx.x + 256] = 0.f;
    __syncthreads();
#pragma unroll
    for (int e = 0; e < 8; ++e) {
        atomicAdd(&sS[cg * 8 + e], s[e]);
        atomicAdd(&sQ[cg * 8 + e], qq[e]);
    }
    __syncthreads();
    for (int cidx = threadIdx.x; cidx < 512; cidx += 256) {
        atomicAdd(&ssum[cidx], sS[cidx]);
        atomicAdd(&ssq[cidx], sQ[cidx]);
    }
}

// 128x128-tile bf16 MFMA GEMM, A [M][lda] bf16, Bt [N][K] bf16.
// global_load_lds width=16 staging, 3-buffer counted-vmcnt pipeline.
// EPI: 1 bias+relu+stats bf16; 2 bias+sigmoid+stats bf16; 4 bias+sigmoid f32; 5 bias bf16
template <int EPI>
__global__ __launch_bounds__(256) void k_gemm(const unsigned short* __restrict__ A, int lda,
                                              const unsigned short* __restrict__ Bt,
                                              void* __restrict__ C, int ldc,
                                              const float* __restrict__ bias,
                                              float* __restrict__ ssum, float* __restrict__ ssq,
                                              int K) {
    const int n0 = blockIdx.x * 128;
    const int m0 = blockIdx.y * 128;
    const int tid = threadIdx.x;
    const int w = tid >> 6;
    const int lane = tid & 63;
    const int q = lane >> 4;
    const int l = lane & 15;
    const int wm = w >> 1;
    const int wn = w & 1;

    __shared__ __align__(16) unsigned short lA[3][128 * 32];  // [m][k]
    __shared__ __align__(16) unsigned short lB[3][128 * 32];  // [n][k]
    __shared__ float s_sum[128];
    __shared__ float s_sq[128];

    if ((EPI == 1 || EPI == 2) && tid < 128) { s_sum[tid] = 0.f; s_sq[tid] = 0.f; }

    f32x4 acc[4][4] = {};

    const int rsub = tid >> 2;          // 0..63
    const int ksub = (tid & 3) * 8;     // 0,8,16,24
    const unsigned short* gA = A + (size_t)(m0 + rsub) * lda + ksub;
    const unsigned short* gB = Bt + (size_t)(n0 + rsub) * K + ksub;
    const unsigned wofs = (unsigned)(tid >> 6) * 1024;  // wave LDS base, bytes

    auto stage = [&](int buf, int k0) {   // 4 DMA ops per wave
        char* la = (char*)lA[buf] + wofs;
        char* lb = (char*)lB[buf] + wofs;
        gld16(gA + k0, la);
        gld16(gA + (size_t)64 * lda + k0, la + 4096);
        gld16(gB + k0, lb);
        gld16(gB + (size_t)64 * K + k0, lb + 4096);
    };

    const int nt = K >> 5;
    stage(0, 0);
    if (nt > 1) stage(1, 32);

    int cur = 0;
    for (int t = 0; t < nt; ++t) {
        // tile t's 4 DMAs done; tile t+1's (if any) may remain in flight
        if (t + 1 < nt) { asm volatile("s_waitcnt vmcnt(4)" ::: "memory"); }
        else            { asm volatile("s_waitcnt vmcnt(0)" ::: "memory"); }
        __builtin_amdgcn_s_barrier();
        __builtin_amdgcn_sched_barrier(0);
        if (t + 2 < nt) {
            int b2 = cur + 2; if (b2 >= 3) b2 -= 3;
            stage(b2, (t + 2) << 5);   // overwrites buf t-1: safe, all reads done
        }
        short8 av[4], bv[4];
#pragma unroll
        for (int i = 0; i < 4; ++i)
            av[i] = *(const short8*)(&lA[cur][(wm * 64 + i * 16 + l) * 32 + q * 8]);
#pragma unroll
        for (int j = 0; j < 4; ++j)
            bv[j] = *(const short8*)(&lB[cur][(wn * 64 + j * 16 + l) * 32 + q * 8]);
#pragma unroll
        for (int i = 0; i < 4; ++i)
#pragma unroll
            for (int j = 0; j < 4; ++j)
                acc[i][j] = __builtin_amdgcn_mfma_f32_16x16x32_bf16(av[i], bv[j], acc[i][j], 0, 0, 0);
        cur = (cur == 2) ? 0 : cur + 1;
    }

#pragma unroll
    for (int j = 0; j < 4; ++j) {
        const int colL = wn * 64 + j * 16 + l;
        const int col = n0 + colL;
        const float bb = bias[col];
        float psum = 0.f, psq = 0.f;
#pragma unroll
        for (int i = 0; i < 4; ++i) {
            const int rowL = wm * 64 + i * 16 + q * 4;
#pragma unroll
            for (int r = 0; r < 4; ++r) {
                float v = acc[i][j][r] + bb;
                if (EPI == 1) v = fmaxf(v, 0.f);
                if (EPI == 2 || EPI == 4) v = sigmoidf_(v);
                const size_t off = (size_t)(m0 + rowL + r) * ldc + col;
                if (EPI == 4) ((float*)C)[off] = v;
                else ((unsigned short*)C)[off] = f2bu(v);
                psum += v; psq += v * v;
            }
        }
        if (EPI == 1 || EPI == 2) {
            atomicAdd(&s_sum[colL], psum);
            atomicAdd(&s_sq[colL], psq);
        }
    }
    if (EPI == 1 || EPI == 2) {
        __syncthreads();
        if (tid < 128) {
            atomicAdd(&ssum[n0 + tid], s_sum[tid]);
            atomicAdd(&ssq[n0 + tid], s_sq[tid]);
        }
    }
}

// Fused message GEMM + in-register mean + bf16 store + column stats.
// 128x256 tile, grid.x = 1: the VALU-expensive A-build runs once per tile.
// Wave grid 2x2, each wave 64 rows x 128 cols, acc[4][8].
// Padded M: row m = 4*node + slot (slot 0..2 = messages, slot 3 = zero pad).
__global__ __launch_bounds__(256) void k_gemm_msg4(const unsigned short* __restrict__ PQ,  // [G][1024] chunk-local
                                                   const unsigned short* __restrict__ Bt,  // A1m [256][512]
                                                   unsigned short* __restrict__ inf_,      // chunk-offset, [G][512] bf16
                                                   const float* __restrict__ bias,         // b1m [256]
                                                   float* __restrict__ ssum,               // sif_s+256
                                                   float* __restrict__ ssq) {              // sif_q+256
    const int K = 512;
    const int m0 = blockIdx.x * 128;          // padded chunk-local msg row base
    const int tid = threadIdx.x;
    const int w = tid >> 6;
    const int lane = tid & 63;
    const int q = lane >> 4;
    const int l = lane & 15;
    const int wm = w >> 1;                    // 0..1: row half
    const int wn = w & 1;                     // 0..1: col half (128 cols each)

    __shared__ __align__(16) unsigned short lA[2][128 * 32];  // 8 KB each
    __shared__ __align__(16) unsigned short lB[2][256 * 32];  // 16 KB each
    __shared__ float s_sum[256];
    __shared__ float s_sq[256];

    s_sum[tid] = 0.f; s_sq[tid] = 0.f;

    f32x4 acc[4][8] = {};

    const int rsub = tid >> 2;          // 0..63
    const int ksub = (tid & 3) * 8;     // 0,8,16,24
    unsigned aP[2], aQ[2], wAo[2];
    bool pad[2];
#pragma unroll
    for (int t = 0; t < 2; ++t) {
        int row = m0 + t * 64 + rsub;    // padded chunk-local msg row
        int node = row >> 2;             // chunk-local node
        int slot = row & 3;
        pad[t] = (slot == 3);
        int si = node & 3;
        int di = slot + (slot >= si ? 1 : 0);
        aP[t] = (unsigned)node * 1024 + ksub;
        aQ[t] = (unsigned)(node - si + di) * 1024 + 512 + ksub;
        wAo[t] = (unsigned)((t * 64 + rsub) * 32 + ksub);
    }
    const unsigned short* gB = Bt + (size_t)rsub * K + ksub;
    const unsigned wofs = (unsigned)w * 1024;

    auto loadPQ = [&](int k0, short8 p8[2], short8 q8[2]) {
#pragma unroll
        for (int t = 0; t < 2; ++t) {
            if (!pad[t]) {
                p8[t] = *(const short8*)(PQ + aP[t] + k0);
                q8[t] = *(const short8*)(PQ + aQ[t] + k0);
            }
        }
    };
    auto buildA = [&](const short8 p8[2], const short8 q8[2], short8 a8[2]) {
#pragma unroll
        for (int t = 0; t < 2; ++t) {
            if (!pad[t]) {
                u32x4 pu = __builtin_bit_cast(u32x4, p8[t]);
                u32x4 qu = __builtin_bit_cast(u32x4, q8[t]);
                u32x4 ou;
#pragma unroll
                for (int i = 0; i < 4; ++i) {
                    float pl = __uint_as_float(pu[i] << 16);
                    float ph = __uint_as_float(pu[i] & 0xffff0000u);
                    float ql = __uint_as_float(qu[i] << 16);
                    float qh = __uint_as_float(qu[i] & 0xffff0000u);
                    float sl = fmaxf(pl + ql, 0.f);
                    float sh = fmaxf(ph + qh, 0.f);
                    unsigned r;
                    asm("v_cvt_pk_bf16_f32 %0, %1, %2" : "=v"(r) : "v"(sl), "v"(sh));
                    ou[i] = r;
                }
                a8[t] = __builtin_bit_cast(short8, ou);
            } else {
                short8 z = {};
                a8[t] = z;
            }
        }
    };
    auto stageB = [&](int buf, int k0) {   // 256 rows per K-step
        char* lb = (char*)lB[buf] + wofs;
#pragma unroll
        for (int t = 0; t < 4; ++t)
            gld16(gB + (size_t)(t * 64) * K + k0, lb + t * 4096);
    };

    // prologue: tile 0
    {
        short8 p8[2], q8[2], a8[2];
        loadPQ(0, p8, q8);
        buildA(p8, q8, a8);
        *(short8*)(&lA[0][wAo[0]]) = a8[0];
        *(short8*)(&lA[0][wAo[1]]) = a8[1];
        stageB(0, 0);
    }
    pipe_barrier();

    const int nt = K >> 5;  // 16
    int cur = 0;
    for (int t = 0; t < nt; ++t) {
        short8 p8[2], q8[2];
        if (t + 1 < nt) {
            loadPQ((t + 1) << 5, p8, q8);   // issue early; consumed after MFMA
            stageB(cur ^ 1, (t + 1) << 5);  // DMA, lands during MFMA
        }
        short8 av[4], bv[8];
#pragma unroll
        for (int i = 0; i < 4; ++i)
            av[i] = *(const short8*)(&lA[cur][(wm * 64 + i * 16 + l) * 32 + q * 8]);
#pragma unroll
        for (int j = 0; j < 8; ++j)
            bv[j] = *(const short8*)(&lB[cur][(wn * 128 + j * 16 + l) * 32 + q * 8]);
#pragma unroll
        for (int i = 0; i < 4; ++i)
#pragma unroll
            for (int j = 0; j < 8; ++j)
                acc[i][j] = __builtin_amdgcn_mfma_f32_16x16x32_bf16(av[i], bv[j], acc[i][j], 0, 0, 0);
        if (t + 1 < nt) {
            short8 a8[2];
            buildA(p8, q8, a8);
            *(short8*)(&lA[cur ^ 1][wAo[0]]) = a8[0];
            *(short8*)(&lA[cur ^ 1][wAo[1]]) = a8[1];
            pipe_barrier();
        }
        cur ^= 1;
    }

#pragma unroll
    for (int j = 0; j < 8; ++j) {
        const int colL = wn * 128 + j * 16 + l;
        const float bb = bias[colL];
        float psum = 0.f, psq = 0.f;
#pragma unroll
        for (int i = 0; i < 4; ++i) {
            const int g = (m0 >> 2) + wm * 16 + i * 4 + q;   // chunk-local node row
            float s0 = sigmoidf_(acc[i][j][0] + bb);
            float s1 = sigmoidf_(acc[i][j][1] + bb);
            float s2 = sigmoidf_(acc[i][j][2] + bb);
            float vm = (s0 + s1 + s2) * (1.f / 3.f);
            inf_[(size_t)g * 512 + 256 + colL] = f2bu(vm);
            psum += vm; psq += vm * vm;
        }
        atomicAdd(&s_sum[colL], psum);
        atomicAdd(&s_sq[colL], psq);
    }
    __syncthreads();
    atomicAdd(&ssum[tid], s_sum[tid]);
    atomicAdd(&ssq[tid], s_sq[tid]);
}

extern "C" void kernel_launch(void* const* d_in, const int* in_sizes, int n_in,
                              void* d_out, int out_size, void* d_ws, size_t ws_size,
                              hipStream_t stream) {
    const float* x   = (const float*)d_in[0];
    const float* ng0 = (const float*)d_in[1];
    const float* nb0 = (const float*)d_in[2];
    const float* nW0 = (const float*)d_in[3];
    const float* nc0 = (const float*)d_in[4];
    const float* ng1 = (const float*)d_in[5];
    const float* nb1 = (const float*)d_in[6];
    const float* nW1 = (const float*)d_in[7];
    const float* nc1 = (const float*)d_in[8];
    const float* mg0 = (const float*)d_in[9];
    const float* mb0 = (const float*)d_in[10];
    const float* mW0 = (const float*)d_in[11];
    const float* mc0 = (const float*)d_in[12];
    const float* mg1 = (const float*)d_in[13];
    const float* mb1 = (const float*)d_in[14];
    const float* mW1 = (const float*)d_in[15];
    const float* mc1 = (const float*)d_in[16];
    const float* fg0 = (const float*)d_in[17];
    const float* fb0 = (const float*)d_in[18];
    const float* fW0 = (const float*)d_in[19];
    const float* fc0 = (const float*)d_in[20];
    const float* fg1 = (const float*)d_in[21];
    const float* fb1 = (const float*)d_in[22];
    const float* fW1 = (const float*)d_in[23];
    const float* fc1 = (const float*)d_in[24];

    char* ws = (char*)d_ws;
    const size_t MiB = 1024 * 1024;

    // chunk count for PQ: peak ws = 100 + 128/Cq MiB (x16 adds 32 MiB)
    int Cq = 1;
    while (Cq < 8 && (100 + 128 / Cq) * MiB > ws_size) Cq *= 2;
    const int G = 65536 / Cq;  // node rows per chunk (multiple of 32)

    // header [0,4MiB): stats (zeroed) + biases + folded weights
    float* stat = (float*)ws;
    float* sx_s   = stat + 0;     // 256
    float* sx_q   = stat + 256;   // 256
    float* shn_s  = stat + 512;   // 512
    float* shn_q  = stat + 1024;
    float* shm_s  = stat + 1536;
    float* shm_q  = stat + 2048;
    float* sif_s  = stat + 2560;
    float* sif_q  = stat + 3072;
    float* shf_s  = stat + 3584;
    float* shf_q  = stat + 4096;  // -> 4608
    float* biasPQ = stat + 4608;  // 1024, upper 512 stay zero
    // zeroed region ends at 5632 floats
    float* bias_n = stat + 5632;  // 512
    float* b1n    = stat + 6144;  // 256
    float* b1m    = stat + 6400;  // 256
    float* b0f    = stat + 6656;  // 512
    float* b1f    = stat + 7168;  // 256

    unsigned short* An  = (unsigned short*)(ws + 256 * 1024);  // [512][256]
    unsigned short* Btm = An + 512 * 256;                      // [1024][256]
    unsigned short* A1n = Btm + 1024 * 256;                    // [256][512]
    unsigned short* A1m = A1n + 256 * 512;                     // [256][512]
    unsigned short* A0f = A1m + 256 * 512;                     // [512][512]
    unsigned short* A1f = A0f + 512 * 512;                     // [256][512]

    // [4,68): hn (bf16, live gemm1..gemm2n) -> hf (bf16, live gemm3..gemm4)
    // [68, 68+128/Cq): PQ chunk buffer
    // [68+128/Cq, +32): x16 bf16 [65536][256]
    unsigned short* hn    = (unsigned short*)(ws + 4 * MiB);
    unsigned short* hf    = (unsigned short*)(ws + 4 * MiB);
    unsigned short* PQbuf = (unsigned short*)(ws + 68 * MiB);
    unsigned short* x16   = (unsigned short*)(ws + (68 + 128 / Cq) * MiB);
    unsigned short* inf   = (unsigned short*)d_out;  // [65536,512] bf16, dead before gemm4

    const float inv1 = 1.f / 65536.f;
    const float invM = 1.f / 196608.f;

    // zero stats + biasPQ (5632 floats = 1408 float4)
    k_zero4<<<6, 256, 0, stream>>>((float4*)stat, 1408);

    // x -> bf16 + column stats (fused)
    k_xcvt<<<1024, 256, 0, stream>>>(x, x16, sx_s, sx_q);

    // fold BN0 (msg BN0 stats == node BN0 stats: each node appears exactly
    // 3x as src and 3x as dst across the 12 ordered pairs)
    k_fold<<<512, 256, 0, stream>>>(nW0, ng0, nb0, sx_s, sx_q, nc0, inv1, 512, 256, An, bias_n, 0);
    k_fold<<<512, 256, 0, stream>>>(mW0, mg0, mb0, sx_s, sx_q, mc0, inv1, 512, 256, Btm, biasPQ, 0);
    k_fold<<<512, 256, 0, stream>>>(mW0 + 256 * 512, mg0 + 256, mb0 + 256, sx_s, sx_q, nullptr,
                                    inv1, 512, 256, Btm + 512 * 256, biasPQ, 1);

    // h_n = relu(x16 @ An + bias_n), BN1_n stats
    k_gemm<1><<<dim3(4, 512), 256, 0, stream>>>(x16, 256, An, hn, 512, bias_n, shn_s, shn_q, 256);

    // PQ chunks: PQ = x16_chunk @ [Amt|Amb] + [bias_m|0]; accumulate BN1_m stats
    for (int c = 0; c < Cq; ++c) {
        k_gemm<5><<<dim3(8, 512 / Cq), 256, 0, stream>>>(
            x16 + (size_t)c * G * 256, 256, Btm, PQbuf, 1024, biasPQ, nullptr, nullptr, 256);
        k_msgstats2<<<1024 / Cq, 256, 0, stream>>>(PQbuf, shm_s, shm_q);
    }

    // fold BN1
    k_fold<<<256, 256, 0, stream>>>(nW1, ng1, nb1, shn_s, shn_q, nc1, inv1, 256, 512, A1n, b1n, 0);
    k_fold<<<256, 256, 0, stream>>>(mW1, mg1, mb1, shm_s, shm_q, mc1, invM, 256, 512, A1m, b1m, 0);

    // x_node = sigmoid(hn @ A1n + b1n) -> in_f[:,0:256] (in d_out), f-BN0 stats
    k_gemm<2><<<dim3(2, 512), 256, 0, stream>>>(hn, 512, A1n, inf, 512, b1n, sif_s, sif_q, 512);

    // x_agg: padded msg GEMM (single n-block, 128x256) -> in_f[:,256:512] bf16
    // + f-BN0 stats (cols 256..511)
    for (int c = 0; c < Cq; ++c) {
        if (Cq > 1)  // recompute PQ chunk (Cq==1 kept the full PQ)
            k_gemm<5><<<dim3(8, 512 / Cq), 256, 0, stream>>>(
                x16 + (size_t)c * G * 256, 256, Btm, PQbuf, 1024, biasPQ, nullptr, nullptr, 256);
        k_gemm_msg4<<<dim3(G / 32), 256, 0, stream>>>(
            PQbuf, A1m, inf + (size_t)c * G * 512, b1m, sif_s + 256, sif_q + 256);
    }

    // final MLP
    k_fold<<<512, 256, 0, stream>>>(fW0, fg0, fb0, sif_s, sif_q, fc0, inv1, 512, 512, A0f, b0f, 0);
    k_gemm<1><<<dim3(4, 512), 256, 0, stream>>>(inf, 512, A0f, hf, 512, b0f, shf_s, shf_q, 512);
    k_fold<<<256, 256, 0, stream>>>(fW1, fg1, fb1, shf_s, shf_q, fc1, inv1, 256, 512, A1f, b1f, 0);
    k_gemm<4><<<dim3(2, 512), 256, 0, stream>>>(hf, 512, A1f, d_out, 256, b1f, nullptr, nullptr, 512);

    (void)in_sizes; (void)n_in; (void)out_size;
}

// Round 6
// 671.061 us; speedup vs baseline: 1.4766x; 1.0267x over previous
//
#include <hip/hip_runtime.h>

// GNNLayer: 3 MLPs (node/message/final). BN folded into GEMM weights.
// bf16 storage, fp32 MFMA accumulation, fp32 stats.
// Round 6: k_gemm_pq = dual-tile PQ GEMM (P cols f + Q cols 512+f in one
// block, shared A staging) with the h_m=relu(P+Q) column stats computed
// IN-REGISTER in the epilogue (each lane's acc quad = one graph's 4 nodes,
// for both P and Q -> all 12 (si,di) pairs are lane-local). Eliminates
// k_msgstats2 (134 MB re-read + full VALU pass) entirely.

typedef __attribute__((ext_vector_type(8))) short short8;
typedef __attribute__((ext_vector_type(4))) float f32x4;
typedef __attribute__((ext_vector_type(4))) unsigned int u32x4;

__device__ __forceinline__ unsigned short f2bu(float f) {
    unsigned int x = __float_as_uint(f);
    x += 0x7fffu + ((x >> 16) & 1u);
    return (unsigned short)(x >> 16);
}
__device__ __forceinline__ float b2f(unsigned short u) {
    return __uint_as_float(((unsigned int)u) << 16);
}
__device__ __forceinline__ float sigmoidf_(float v) {
    return 1.0f / (1.0f + __expf(-v));
}

// async global->LDS DMA, 16 B per lane; LDS dest = wave-uniform base + lane*16
__device__ __forceinline__ void gld16(const void* g, void* l) {
    __builtin_amdgcn_global_load_lds(
        (const __attribute__((address_space(1))) void*)g,
        (__attribute__((address_space(3))) void*)l, 16, 0, 0);
}

// pipeline barrier: drain DMA + LDS ops, raw barrier
__device__ __forceinline__ void pipe_barrier() {
    asm volatile("s_waitcnt vmcnt(0) lgkmcnt(0)" ::: "memory");
    __builtin_amdgcn_s_barrier();
    __builtin_amdgcn_sched_barrier(0);
}

__global__ __launch_bounds__(256) void k_zero4(float4* p, int n4) {
    int i = blockIdx.x * 256 + threadIdx.x;
    if (i < n4) p[i] = make_float4(0.f, 0.f, 0.f, 0.f);
}

// x fp32 -> bf16 copy + per-feature sum/sumsq (fused)
__global__ __launch_bounds__(256) void k_xcvt(const float* __restrict__ x,
                                              unsigned short* __restrict__ x16,
                                              float* __restrict__ ssum,
                                              float* __restrict__ ssq) {
    const int c = threadIdx.x;
    const int r0 = blockIdx.x * 64;
    float s = 0.f, q = 0.f;
    for (int r = r0; r < r0 + 64; ++r) {
        float v = x[(size_t)r * 256 + c];
        x16[(size_t)r * 256 + c] = f2bu(v);
        s += v; q += v * v;
    }
    atomicAdd(&ssum[c], s);
    atomicAdd(&ssq[c], q);
}

// fold BN into weights: Bt[j][k] = s_k*W[k][j] (bf16, [N][K]);
// bias[j] (+)= c[j] + sum_k t_k*W[k][j]. One block per output column j.
__global__ __launch_bounds__(256) void k_fold(const float* __restrict__ W,      // [Kc][N]
                                              const float* __restrict__ gamma,
                                              const float* __restrict__ beta,
                                              const float* __restrict__ ssum,
                                              const float* __restrict__ ssq,
                                              const float* __restrict__ cvec,   // [N] or null
                                              float inv_count, int N, int Kc,
                                              unsigned short* __restrict__ Bt,  // [N][Kc]
                                              float* __restrict__ bias, int bias_add) {
    const int j = blockIdx.x;
    const int t = threadIdx.x;
    float part = 0.f;
    for (int k = t; k < Kc; k += 256) {
        float mu  = ssum[k] * inv_count;
        float var = ssq[k] * inv_count - mu * mu;
        float s   = gamma[k] * rsqrtf(var + 1e-5f);
        float tt  = beta[k] - mu * s;
        float w   = W[(size_t)k * N + j];
        Bt[(size_t)j * Kc + k] = f2bu(s * w);
        part += tt * w;
    }
    __shared__ float red[256];
    red[t] = part;
    __syncthreads();
    for (int s2 = 128; s2 > 0; s2 >>= 1) {
        if (t < s2) red[t] += red[t + s2];
        __syncthreads();
    }
    if (t == 0) {
        if (bias_add) atomicAdd(&bias[j], red[0]);
        else bias[j] = red[0] + cvec[j];
    }
}

// 128x128-tile bf16 MFMA GEMM, A [M][lda] bf16, Bt [N][K] bf16.
// global_load_lds width=16 staging, 3-buffer counted-vmcnt pipeline.
// EPI: 1 bias+relu+stats bf16; 2 bias+sigmoid+stats bf16; 4 bias+sigmoid f32
template <int EPI>
__global__ __launch_bounds__(256) void k_gemm(const unsigned short* __restrict__ A, int lda,
                                              const unsigned short* __restrict__ Bt,
                                              void* __restrict__ C, int ldc,
                                              const float* __restrict__ bias,
                                              float* __restrict__ ssum, float* __restrict__ ssq,
                                              int K) {
    const int n0 = blockIdx.x * 128;
    const int m0 = blockIdx.y * 128;
    const int tid = threadIdx.x;
    const int w = tid >> 6;
    const int lane = tid & 63;
    const int q = lane >> 4;
    const int l = lane & 15;
    const int wm = w >> 1;
    const int wn = w & 1;

    __shared__ __align__(16) unsigned short lA[3][128 * 32];  // [m][k]
    __shared__ __align__(16) unsigned short lB[3][128 * 32];  // [n][k]
    __shared__ float s_sum[128];
    __shared__ float s_sq[128];

    if ((EPI == 1 || EPI == 2) && tid < 128) { s_sum[tid] = 0.f; s_sq[tid] = 0.f; }

    f32x4 acc[4][4] = {};

    const int rsub = tid >> 2;          // 0..63
    const int ksub = (tid & 3) * 8;     // 0,8,16,24
    const unsigned short* gA = A + (size_t)(m0 + rsub) * lda + ksub;
    const unsigned short* gB = Bt + (size_t)(n0 + rsub) * K + ksub;
    const unsigned wofs = (unsigned)(tid >> 6) * 1024;  // wave LDS base, bytes

    auto stage = [&](int buf, int k0) {   // 4 DMA ops per wave
        char* la = (char*)lA[buf] + wofs;
        char* lb = (char*)lB[buf] + wofs;
        gld16(gA + k0, la);
        gld16(gA + (size_t)64 * lda + k0, la + 4096);
        gld16(gB + k0, lb);
        gld16(gB + (size_t)64 * K + k0, lb + 4096);
    };

    const int nt = K >> 5;
    stage(0, 0);
    if (nt > 1) stage(1, 32);

    int cur = 0;
    for (int t = 0; t < nt; ++t) {
        // tile t's 4 DMAs done; tile t+1's (if any) may remain in flight
        if (t + 1 < nt) { asm volatile("s_waitcnt vmcnt(4)" ::: "memory"); }
        else            { asm volatile("s_waitcnt vmcnt(0)" ::: "memory"); }
        __builtin_amdgcn_s_barrier();
        __builtin_amdgcn_sched_barrier(0);
        if (t + 2 < nt) {
            int b2 = cur + 2; if (b2 >= 3) b2 -= 3;
            stage(b2, (t + 2) << 5);   // overwrites buf t-1: safe, all reads done
        }
        short8 av[4], bv[4];
#pragma unroll
        for (int i = 0; i < 4; ++i)
            av[i] = *(const short8*)(&lA[cur][(wm * 64 + i * 16 + l) * 32 + q * 8]);
#pragma unroll
        for (int j = 0; j < 4; ++j)
            bv[j] = *(const short8*)(&lB[cur][(wn * 64 + j * 16 + l) * 32 + q * 8]);
#pragma unroll
        for (int i = 0; i < 4; ++i)
#pragma unroll
            for (int j = 0; j < 4; ++j)
                acc[i][j] = __builtin_amdgcn_mfma_f32_16x16x32_bf16(av[i], bv[j], acc[i][j], 0, 0, 0);
        cur = (cur == 2) ? 0 : cur + 1;
    }

#pragma unroll
    for (int j = 0; j < 4; ++j) {
        const int colL = wn * 64 + j * 16 + l;
        const int col = n0 + colL;
        const float bb = bias[col];
        float psum = 0.f, psq = 0.f;
#pragma unroll
        for (int i = 0; i < 4; ++i) {
            const int rowL = wm * 64 + i * 16 + q * 4;
#pragma unroll
            for (int r = 0; r < 4; ++r) {
                float v = acc[i][j][r] + bb;
                if (EPI == 1) v = fmaxf(v, 0.f);
                if (EPI == 2 || EPI == 4) v = sigmoidf_(v);
                const size_t off = (size_t)(m0 + rowL + r) * ldc + col;
                if (EPI == 4) ((float*)C)[off] = v;
                else ((unsigned short*)C)[off] = f2bu(v);
                psum += v; psq += v * v;
            }
        }
        if (EPI == 1 || EPI == 2) {
            atomicAdd(&s_sum[colL], psum);
            atomicAdd(&s_sq[colL], psq);
        }
    }
    if (EPI == 1 || EPI == 2) {
        __syncthreads();
        if (tid < 128) {
            atomicAdd(&ssum[n0 + tid], s_sum[tid]);
            atomicAdd(&ssq[n0 + tid], s_sq[tid]);
        }
    }
}

// Dual-tile PQ GEMM + fused h_m stats.
// Block: 128 node rows x 128 f-cols, computing BOTH P (Btm rows f0+)
// and Q (Btm rows 512+f0+) against a shared A-tile. Epilogue: each lane's
// acc quad holds one graph's 4 nodes for P and Q at its column -> the 12
// (si,di) relu(P+Q) pair stats are lane-local. Writes P/Q to PQbuf
// (P with bias, matching the old EPI=5 path). STATS=0 for recompute pass.
template <int STATS>
__global__ __launch_bounds__(256) void k_gemm_pq(const unsigned short* __restrict__ A,   // x16 chunk [G][256]
                                                 const unsigned short* __restrict__ Bt,  // Btm [1024][256]
                                                 unsigned short* __restrict__ PQ,        // [G][1024]
                                                 const float* __restrict__ biasP,        // biasPQ [512]
                                                 float* __restrict__ ssum,               // shm_s
                                                 float* __restrict__ ssq) {              // shm_q
    const int K = 256;
    const int f0 = blockIdx.x * 128;
    const int m0 = blockIdx.y * 128;
    const int tid = threadIdx.x;
    const int w = tid >> 6;
    const int lane = tid & 63;
    const int q = lane >> 4;
    const int l = lane & 15;
    const int wm = w >> 1;
    const int wn = w & 1;

    __shared__ __align__(16) unsigned short lA[2][128 * 32];  // 8 KB each
    __shared__ __align__(16) unsigned short lB[2][256 * 32];  // 16 KB each (P rows 0-127, Q rows 128-255)
    __shared__ float s_sum[128];
    __shared__ float s_sq[128];

    if (STATS && tid < 128) { s_sum[tid] = 0.f; s_sq[tid] = 0.f; }

    f32x4 accP[4][4] = {};
    f32x4 accQ[4][4] = {};

    const int rsub = tid >> 2;          // 0..63
    const int ksub = (tid & 3) * 8;     // 0,8,16,24
    const unsigned short* gA  = A  + (size_t)(m0 + rsub) * 256 + ksub;
    const unsigned short* gBP = Bt + (size_t)(f0 + rsub) * K + ksub;
    const unsigned short* gBQ = Bt + (size_t)(512 + f0 + rsub) * K + ksub;
    const unsigned wofs = (unsigned)w * 1024;

    auto stage = [&](int buf, int k0) {   // 6 DMA ops per wave
        char* la = (char*)lA[buf] + wofs;
        char* lb = (char*)lB[buf] + wofs;
        gld16(gA + k0, la);
        gld16(gA + (size_t)64 * 256 + k0, la + 4096);
        gld16(gBP + k0, lb);
        gld16(gBP + (size_t)64 * K + k0, lb + 4096);
        gld16(gBQ + k0, lb + 8192);
        gld16(gBQ + (size_t)64 * K + k0, lb + 12288);
    };

    stage(0, 0);
    pipe_barrier();

    const int nt = K >> 5;  // 8
    int cur = 0;
    for (int t = 0; t < nt; ++t) {
        if (t + 1 < nt) stage(cur ^ 1, (t + 1) << 5);  // DMA lands during MFMA
        short8 av[4], bvP[4], bvQ[4];
#pragma unroll
        for (int i = 0; i < 4; ++i)
            av[i] = *(const short8*)(&lA[cur][(wm * 64 + i * 16 + l) * 32 + q * 8]);
#pragma unroll
        for (int j = 0; j < 4; ++j) {
            bvP[j] = *(const short8*)(&lB[cur][(wn * 64 + j * 16 + l) * 32 + q * 8]);
            bvQ[j] = *(const short8*)(&lB[cur][(128 + wn * 64 + j * 16 + l) * 32 + q * 8]);
        }
#pragma unroll
        for (int i = 0; i < 4; ++i)
#pragma unroll
            for (int j = 0; j < 4; ++j) {
                accP[i][j] = __builtin_amdgcn_mfma_f32_16x16x32_bf16(av[i], bvP[j], accP[i][j], 0, 0, 0);
                accQ[i][j] = __builtin_amdgcn_mfma_f32_16x16x32_bf16(av[i], bvQ[j], accQ[i][j], 0, 0, 0);
            }
        if (t + 1 < nt) pipe_barrier();
        cur ^= 1;
    }

#pragma unroll
    for (int j = 0; j < 4; ++j) {
        const int colL = wn * 64 + j * 16 + l;   // 0..127
        const int f = f0 + colL;
        const float bb = biasP[f];
        float s = 0.f, qq = 0.f;
#pragma unroll
        for (int i = 0; i < 4; ++i) {
            const int rowb = m0 + wm * 64 + i * 16 + q * 4;   // %4==0: one graph
            float p[4], qv[4];
#pragma unroll
            for (int r = 0; r < 4; ++r) {
                p[r]  = accP[i][j][r] + bb;
                qv[r] = accQ[i][j][r];
                PQ[(size_t)(rowb + r) * 1024 + f]       = f2bu(p[r]);
                PQ[(size_t)(rowb + r) * 1024 + 512 + f] = f2bu(qv[r]);
            }
            if (STATS) {
#pragma unroll
                for (int si = 0; si < 4; ++si)
#pragma unroll
                    for (int di = 0; di < 4; ++di) {
                        if (si == di) continue;
                        float v = fmaxf(p[si] + qv[di], 0.f);
                        s += v; qq += v * v;
                    }
            }
        }
        if (STATS) {
            atomicAdd(&s_sum[colL], s);
            atomicAdd(&s_sq[colL], qq);
        }
    }
    if (STATS) {
        __syncthreads();
        if (tid < 128) {
            atomicAdd(&ssum[f0 + tid], s_sum[tid]);
            atomicAdd(&ssq[f0 + tid], s_sq[tid]);
        }
    }
}

// Fused message GEMM + in-register mean + bf16 store + column stats.
// 128x256 tile, grid.x = 1; wave grid 2x2, acc[4][8].
// Padded M: row m = 4*node + slot (slot 0..2 = messages, slot 3 = zero pad).
__global__ __launch_bounds__(256) void k_gemm_msg4(const unsigned short* __restrict__ PQ,  // [G][1024] chunk-local
                                                   const unsigned short* __restrict__ Bt,  // A1m [256][512]
                                                   unsigned short* __restrict__ inf_,      // chunk-offset, [G][512] bf16
                                                   const float* __restrict__ bias,         // b1m [256]
                                                   float* __restrict__ ssum,               // sif_s+256
                                                   float* __restrict__ ssq) {              // sif_q+256
    const int K = 512;
    const int m0 = blockIdx.x * 128;          // padded chunk-local msg row base
    const int tid = threadIdx.x;
    const int w = tid >> 6;
    const int lane = tid & 63;
    const int q = lane >> 4;
    const int l = lane & 15;
    const int wm = w >> 1;                    // 0..1: row half
    const int wn = w & 1;                     // 0..1: col half (128 cols each)

    __shared__ __align__(16) unsigned short lA[2][128 * 32];  // 8 KB each
    __shared__ __align__(16) unsigned short lB[2][256 * 32];  // 16 KB each
    __shared__ float s_sum[256];
    __shared__ float s_sq[256];

    s_sum[tid] = 0.f; s_sq[tid] = 0.f;

    f32x4 acc[4][8] = {};

    const int rsub = tid >> 2;          // 0..63
    const int ksub = (tid & 3) * 8;     // 0,8,16,24
    unsigned aP[2], aQ[2], wAo[2];
    bool pad[2];
#pragma unroll
    for (int t = 0; t < 2; ++t) {
        int row = m0 + t * 64 + rsub;    // padded chunk-local msg row
        int node = row >> 2;             // chunk-local node
        int slot = row & 3;
        pad[t] = (slot == 3);
        int si = node & 3;
        int di = slot + (slot >= si ? 1 : 0);
        aP[t] = (unsigned)node * 1024 + ksub;
        aQ[t] = (unsigned)(node - si + di) * 1024 + 512 + ksub;
        wAo[t] = (unsigned)((t * 64 + rsub) * 32 + ksub);
    }
    const unsigned short* gB = Bt + (size_t)rsub * K + ksub;
    const unsigned wofs = (unsigned)w * 1024;

    auto loadPQ = [&](int k0, short8 p8[2], short8 q8[2]) {
#pragma unroll
        for (int t = 0; t < 2; ++t) {
            if (!pad[t]) {
                p8[t] = *(const short8*)(PQ + aP[t] + k0);
                q8[t] = *(const short8*)(PQ + aQ[t] + k0);
            }
        }
    };
    auto buildA = [&](const short8 p8[2], const short8 q8[2], short8 a8[2]) {
#pragma unroll
        for (int t = 0; t < 2; ++t) {
            if (!pad[t]) {
                u32x4 pu = __builtin_bit_cast(u32x4, p8[t]);
                u32x4 qu = __builtin_bit_cast(u32x4, q8[t]);
                u32x4 ou;
#pragma unroll
                for (int i = 0; i < 4; ++i) {
                    float pl = __uint_as_float(pu[i] << 16);
                    float ph = __uint_as_float(pu[i] & 0xffff0000u);
                    float ql = __uint_as_float(qu[i] << 16);
                    float qh = __uint_as_float(qu[i] & 0xffff0000u);
                    float sl = fmaxf(pl + ql, 0.f);
                    float sh = fmaxf(ph + qh, 0.f);
                    unsigned r;
                    asm("v_cvt_pk_bf16_f32 %0, %1, %2" : "=v"(r) : "v"(sl), "v"(sh));
                    ou[i] = r;
                }
                a8[t] = __builtin_bit_cast(short8, ou);
            } else {
                short8 z = {};
                a8[t] = z;
            }
        }
    };
    auto stageB = [&](int buf, int k0) {   // 256 rows per K-step
        char* lb = (char*)lB[buf] + wofs;
#pragma unroll
        for (int t = 0; t < 4; ++t)
            gld16(gB + (size_t)(t * 64) * K + k0, lb + t * 4096);
    };

    // prologue: tile 0
    {
        short8 p8[2], q8[2], a8[2];
        loadPQ(0, p8, q8);
        buildA(p8, q8, a8);
        *(short8*)(&lA[0][wAo[0]]) = a8[0];
        *(short8*)(&lA[0][wAo[1]]) = a8[1];
        stageB(0, 0);
    }
    pipe_barrier();

    const int nt = K >> 5;  // 16
    int cur = 0;
    for (int t = 0; t < nt; ++t) {
        short8 p8[2], q8[2];
        if (t + 1 < nt) {
            loadPQ((t + 1) << 5, p8, q8);   // issue early; consumed after MFMA
            stageB(cur ^ 1, (t + 1) << 5);  // DMA, lands during MFMA
        }
        short8 av[4], bv[8];
#pragma unroll
        for (int i = 0; i < 4; ++i)
            av[i] = *(const short8*)(&lA[cur][(wm * 64 + i * 16 + l) * 32 + q * 8]);
#pragma unroll
        for (int j = 0; j < 8; ++j)
            bv[j] = *(const short8*)(&lB[cur][(wn * 128 + j * 16 + l) * 32 + q * 8]);
#pragma unroll
        for (int i = 0; i < 4; ++i)
#pragma unroll
            for (int j = 0; j < 8; ++j)
                acc[i][j] = __builtin_amdgcn_mfma_f32_16x16x32_bf16(av[i], bv[j], acc[i][j], 0, 0, 0);
        if (t + 1 < nt) {
            short8 a8[2];
            buildA(p8, q8, a8);
            *(short8*)(&lA[cur ^ 1][wAo[0]]) = a8[0];
            *(short8*)(&lA[cur ^ 1][wAo[1]]) = a8[1];
            pipe_barrier();
        }
        cur ^= 1;
    }

#pragma unroll
    for (int j = 0; j < 8; ++j) {
        const int colL = wn * 128 + j * 16 + l;
        const float bb = bias[colL];
        float psum = 0.f, psq = 0.f;
#pragma unroll
        for (int i = 0; i < 4; ++i) {
            const int g = (m0 >> 2) + wm * 16 + i * 4 + q;   // chunk-local node row
            float s0 = sigmoidf_(acc[i][j][0] + bb);
            float s1 = sigmoidf_(acc[i][j][1] + bb);
            float s2 = sigmoidf_(acc[i][j][2] + bb);
            float vm = (s0 + s1 + s2) * (1.f / 3.f);
            inf_[(size_t)g * 512 + 256 + colL] = f2bu(vm);
            psum += vm; psq += vm * vm;
        }
        atomicAdd(&s_sum[colL], psum);
        atomicAdd(&s_sq[colL], psq);
    }
    __syncthreads();
    atomicAdd(&ssum[tid], s_sum[tid]);
    atomicAdd(&ssq[tid], s_sq[tid]);
}

extern "C" void kernel_launch(void* const* d_in, const int* in_sizes, int n_in,
                              void* d_out, int out_size, void* d_ws, size_t ws_size,
                              hipStream_t stream) {
    const float* x   = (const float*)d_in[0];
    const float* ng0 = (const float*)d_in[1];
    const float* nb0 = (const float*)d_in[2];
    const float* nW0 = (const float*)d_in[3];
    const float* nc0 = (const float*)d_in[4];
    const float* ng1 = (const float*)d_in[5];
    const float* nb1 = (const float*)d_in[6];
    const float* nW1 = (const float*)d_in[7];
    const float* nc1 = (const float*)d_in[8];
    const float* mg0 = (const float*)d_in[9];
    const float* mb0 = (const float*)d_in[10];
    const float* mW0 = (const float*)d_in[11];
    const float* mc0 = (const float*)d_in[12];
    const float* mg1 = (const float*)d_in[13];
    const float* mb1 = (const float*)d_in[14];
    const float* mW1 = (const float*)d_in[15];
    const float* mc1 = (const float*)d_in[16];
    const float* fg0 = (const float*)d_in[17];
    const float* fb0 = (const float*)d_in[18];
    const float* fW0 = (const float*)d_in[19];
    const float* fc0 = (const float*)d_in[20];
    const float* fg1 = (const float*)d_in[21];
    const float* fb1 = (const float*)d_in[22];
    const float* fW1 = (const float*)d_in[23];
    const float* fc1 = (const float*)d_in[24];

    char* ws = (char*)d_ws;
    const size_t MiB = 1024 * 1024;

    // chunk count for PQ: peak ws = 100 + 128/Cq MiB (x16 adds 32 MiB)
    int Cq = 1;
    while (Cq < 8 && (100 + 128 / Cq) * MiB > ws_size) Cq *= 2;
    const int G = 65536 / Cq;  // node rows per chunk (multiple of 128)

    // header [0,4MiB): stats (zeroed) + biases + folded weights
    float* stat = (float*)ws;
    float* sx_s   = stat + 0;     // 256
    float* sx_q   = stat + 256;   // 256
    float* shn_s  = stat + 512;   // 512
    float* shn_q  = stat + 1024;
    float* shm_s  = stat + 1536;
    float* shm_q  = stat + 2048;
    float* sif_s  = stat + 2560;
    float* sif_q  = stat + 3072;
    float* shf_s  = stat + 3584;
    float* shf_q  = stat + 4096;  // -> 4608
    float* biasPQ = stat + 4608;  // 1024, upper 512 stay zero
    // zeroed region ends at 5632 floats
    float* bias_n = stat + 5632;  // 512
    float* b1n    = stat + 6144;  // 256
    float* b1m    = stat + 6400;  // 256
    float* b0f    = stat + 6656;  // 512
    float* b1f    = stat + 7168;  // 256

    unsigned short* An  = (unsigned short*)(ws + 256 * 1024);  // [512][256]
    unsigned short* Btm = An + 512 * 256;                      // [1024][256]
    unsigned short* A1n = Btm + 1024 * 256;                    // [256][512]
    unsigned short* A1m = A1n + 256 * 512;                     // [256][512]
    unsigned short* A0f = A1m + 256 * 512;                     // [512][512]
    unsigned short* A1f = A0f + 512 * 512;                     // [256][512]

    // [4,68): hn (bf16, live gemm1..gemm2n) -> hf (bf16, live gemm3..gemm4)
    // [68, 68+128/Cq): PQ chunk buffer
    // [68+128/Cq, +32): x16 bf16 [65536][256]
    unsigned short* hn    = (unsigned short*)(ws + 4 * MiB);
    unsigned short* hf    = (unsigned short*)(ws + 4 * MiB);
    unsigned short* PQbuf = (unsigned short*)(ws + 68 * MiB);
    unsigned short* x16   = (unsigned short*)(ws + (68 + 128 / Cq) * MiB);
    unsigned short* inf   = (unsigned short*)d_out;  // [65536,512] bf16, dead before gemm4

    const float inv1 = 1.f / 65536.f;
    const float invM = 1.f / 196608.f;

    // zero stats + biasPQ (5632 floats = 1408 float4)
    k_zero4<<<6, 256, 0, stream>>>((float4*)stat, 1408);

    // x -> bf16 + column stats (fused)
    k_xcvt<<<1024, 256, 0, stream>>>(x, x16, sx_s, sx_q);

    // fold BN0 (msg BN0 stats == node BN0 stats: each node appears exactly
    // 3x as src and 3x as dst across the 12 ordered pairs)
    k_fold<<<512, 256, 0, stream>>>(nW0, ng0, nb0, sx_s, sx_q, nc0, inv1, 512, 256, An, bias_n, 0);
    k_fold<<<512, 256, 0, stream>>>(mW0, mg0, mb0, sx_s, sx_q, mc0, inv1, 512, 256, Btm, biasPQ, 0);
    k_fold<<<512, 256, 0, stream>>>(mW0 + 256 * 512, mg0 + 256, mb0 + 256, sx_s, sx_q, nullptr,
                                    inv1, 512, 256, Btm + 512 * 256, biasPQ, 1);

    // h_n = relu(x16 @ An + bias_n), BN1_n stats
    k_gemm<1><<<dim3(4, 512), 256, 0, stream>>>(x16, 256, An, hn, 512, bias_n, shn_s, shn_q, 256);

    // PQ chunks: dual-tile P/Q GEMM with fused h_m stats (replaces PQ gemm + msgstats)
    for (int c = 0; c < Cq; ++c) {
        k_gemm_pq<1><<<dim3(4, G / 128), 256, 0, stream>>>(
            x16 + (size_t)c * G * 256, Btm, PQbuf, biasPQ, shm_s, shm_q);
    }

    // fold BN1
    k_fold<<<256, 256, 0, stream>>>(nW1, ng1, nb1, shn_s, shn_q, nc1, inv1, 256, 512, A1n, b1n, 0);
    k_fold<<<256, 256, 0, stream>>>(mW1, mg1, mb1, shm_s, shm_q, mc1, invM, 256, 512, A1m, b1m, 0);

    // x_node = sigmoid(hn @ A1n + b1n) -> in_f[:,0:256] (in d_out), f-BN0 stats
    k_gemm<2><<<dim3(2, 512), 256, 0, stream>>>(hn, 512, A1n, inf, 512, b1n, sif_s, sif_q, 512);

    // x_agg: padded msg GEMM (single n-block, 128x256) -> in_f[:,256:512] bf16
    // + f-BN0 stats (cols 256..511)
    for (int c = 0; c < Cq; ++c) {
        if (Cq > 1)  // recompute PQ chunk without stats (Cq==1 kept the full PQ)
            k_gemm_pq<0><<<dim3(4, G / 128), 256, 0, stream>>>(
                x16 + (size_t)c * G * 256, Btm, PQbuf, biasPQ, nullptr, nullptr);
        k_gemm_msg4<<<dim3(G / 32), 256, 0, stream>>>(
            PQbuf, A1m, inf + (size_t)c * G * 512, b1m, sif_s + 256, sif_q + 256);
    }

    // final MLP
    k_fold<<<512, 256, 0, stream>>>(fW0, fg0, fb0, sif_s, sif_q, fc0, inv1, 512, 512, A0f, b0f, 0);
    k_gemm<1><<<dim3(4, 512), 256, 0, stream>>>(inf, 512, A0f, hf, 512, b0f, shf_s, shf_q, 512);
    k_fold<<<256, 256, 0, stream>>>(fW1, fg1, fb1, shf_s, shf_q, fc1, inv1, 256, 512, A1f, b1f, 0);
    k_gemm<4><<<dim3(2, 512), 256, 0, stream>>>(hf, 512, A1f, d_out, 256, b1f, nullptr, nullptr, 512);

    (void)in_sizes; (void)n_in; (void)out_size;
}